// Round 11
// baseline (2723.742 us; speedup 1.0000x reference)
//
#include <hip/hip_runtime.h>
#include <math.h>

#define DEV __device__ __forceinline__

typedef __attribute__((ext_vector_type(8))) _Float16 f16x8;
typedef __attribute__((ext_vector_type(8))) short short8;
typedef __attribute__((ext_vector_type(4))) float f32x4;

namespace {

constexpr int C = 512;
constexpr int ROWS = 32768;   // B * L
constexpr float LSCALE = 2048.0f;        // lo-plane pre-scale (2^11)
constexpr float LINV   = 1.0f / 2048.0f;
constexpr float F16MIN = 6.1035156e-5f;  // fp16 min normal

// fp32 -> fp16 hi/lo split. h = RTN(x) (flushed to 0 below normal range),
// l = RTN((x - h) * 2^11). Ensures all MFMA inputs are 0 or normal fp16.
DEV void f2hsplit(float x, short& hs, short& ls) {
  _Float16 h = (_Float16)x;
  float hf = (float)h;
  if (fabsf(hf) < F16MIN) { h = (_Float16)0.0f; hf = 0.f; }
  _Float16 l = (_Float16)((x - hf) * LSCALE);
  if (fabsf((float)l) < F16MIN) l = (_Float16)0.0f;
  hs = __builtin_bit_cast(short, h);
  ls = __builtin_bit_cast(short, l);
}

DEV unsigned umn(unsigned a, unsigned b) { return a < b ? a : b; }
DEV unsigned umx(unsigned a, unsigned b) { return a > b ? a : b; }

// monotone key: high 20 bits = sign-flipped fp32 distance, low 12 = col idx.
DEV unsigned packkey(float d, int col) {
  unsigned u = __builtin_bit_cast(unsigned, d);
  u = (u & 0x80000000u) ? ~u : (u | 0x80000000u);
  return (u & 0xFFFFF000u) | (unsigned)col;
}
DEV float unpackd(unsigned k) {
  unsigned u = (k & 0x80000000u) ? (k ^ 0x80000000u) : ~k;
  return __builtin_bit_cast(float, u);
}

// windowed row r -> flat row in (b, y, x) order, for roll by `shift`.
DEV int rowmap(int r, int shift) {
  int b  = r >> 10;
  int w  = (r >> 6) & 15;
  int wy = w >> 2, wx = w & 3;
  int ii = r & 63;
  int iy = ii >> 3, ix = ii & 7;
  int y = (wy * 8 + iy + shift) & 31;
  int x = (wx * 8 + ix + shift) & 31;
  return (b << 10) + (y << 5) + x;
}

DEV int region(int y) { return (y < 24) ? 0 : ((y < 28) ? 1 : 2); }

typedef __attribute__((address_space(1))) const unsigned int gu32;
typedef __attribute__((address_space(3))) unsigned int lu32;
DEV void gload16(const void* g, void* l) {
  __builtin_amdgcn_global_load_lds((gu32*)g, (lu32*)l, 16, 0, 0);
}

// ---------------- LayerNorm -> fp16 hi/lo planes ---------------------------
__global__ __launch_bounds__(256) void ln_split_kernel(
    const float* __restrict__ src, short* __restrict__ Hp, short* __restrict__ Lp,
    const float* __restrict__ g, const float* __restrict__ b,
    int shift, int windowed) {
  int wid  = (blockIdx.x * 256 + threadIdx.x) >> 6;
  int lane = threadIdx.x & 63;
  if (wid >= ROWS) return;
  int srcRow = windowed ? rowmap(wid, shift) : wid;
  const float* s = src + (size_t)srcRow * C + lane * 8;
  float v[8];
  *(float4*)(v)     = *(const float4*)(s);
  *(float4*)(v + 4) = *(const float4*)(s + 4);
  float sum = 0.f;
#pragma unroll
  for (int j = 0; j < 8; j++) sum += v[j];
#pragma unroll
  for (int o = 32; o >= 1; o >>= 1) sum += __shfl_xor(sum, o);
  float mu = sum * (1.0f / 512.0f);
  float vs = 0.f;
#pragma unroll
  for (int j = 0; j < 8; j++) { float d = v[j] - mu; vs += d * d; }
#pragma unroll
  for (int o = 32; o >= 1; o >>= 1) vs += __shfl_xor(vs, o);
  float rs = rsqrtf(vs * (1.0f / 512.0f) + 1e-5f);
  float gg[8], bb[8];
  *(float4*)gg       = *(const float4*)&g[lane * 8];
  *(float4*)(gg + 4) = *(const float4*)&g[lane * 8 + 4];
  *(float4*)bb       = *(const float4*)&b[lane * 8];
  *(float4*)(bb + 4) = *(const float4*)&b[lane * 8 + 4];
  short8 hv, lv;
#pragma unroll
  for (int j = 0; j < 8; j++) {
    float o8 = (v[j] - mu) * rs * gg[j] + bb[j];
    short hh, ll;
    f2hsplit(o8, hh, ll);
    hv[j] = hh; lv[j] = ll;
  }
  *(short8*)&Hp[(size_t)wid * C + lane * 8] = hv;
  *(short8*)&Lp[(size_t)wid * C + lane * 8] = lv;
}

// ---------------- row sum of squares (codebook) ----------------------------
__global__ __launch_bounds__(256) void rowss_kernel(
    const float* __restrict__ src, float* __restrict__ dst, int nrows) {
  int wid  = (blockIdx.x * 256 + threadIdx.x) >> 6;
  int lane = threadIdx.x & 63;
  if (wid >= nrows) return;
  const float* s = src + (size_t)wid * C + lane * 8;
  float4 a  = *(const float4*)s;
  float4 b4 = *(const float4*)(s + 4);
  float sum = a.x*a.x + a.y*a.y + a.z*a.z + a.w*a.w
            + b4.x*b4.x + b4.y*b4.y + b4.z*b4.z + b4.w*b4.w;
#pragma unroll
  for (int o = 32; o >= 1; o >>= 1) sum += __shfl_xor(sum, o);
  if (lane == 0) dst[wid] = sum;
}

// ---------------- weight transpose + split: W(K,N) -> H/L (N,K) ------------
__global__ __launch_bounds__(256) void wconvT_kernel(
    const float* __restrict__ W, short* __restrict__ Hp, short* __restrict__ Lp,
    int K, int N) {
  __shared__ float t[32][33];
  int tx = threadIdx.x, ty = threadIdx.y;
  int n0 = blockIdx.x * 32, k0 = blockIdx.y * 32;
#pragma unroll
  for (int r = 0; r < 4; r++) {
    int k = ty + r * 8;
    t[k][tx] = W[(size_t)(k0 + k) * N + n0 + tx];
  }
  __syncthreads();
#pragma unroll
  for (int r = 0; r < 4; r++) {
    int n = ty + r * 8;
    short h, l;
    f2hsplit(t[tx][n], h, l);
    Hp[(size_t)(n0 + n) * K + k0 + tx] = h;
    Lp[(size_t)(n0 + n) * K + k0 + tx] = l;
  }
}

// ---------------- codebook split (already N-major) -------------------------
__global__ __launch_bounds__(256) void wconv_kernel(
    const float* __restrict__ W, short* __restrict__ Hp, short* __restrict__ Lp) {
  size_t i = ((size_t)blockIdx.x * 256 + threadIdx.x) * 4;
  float4 a = *(const float4*)&W[i];
  float v[4] = {a.x, a.y, a.z, a.w};
  short hv[4], lv[4];
#pragma unroll
  for (int j = 0; j < 4; j++) f2hsplit(v[j], hv[j], lv[j]);
  *(short4*)&Hp[i] = *(short4*)hv;
  *(short4*)&Lp[i] = *(short4*)lv;
}

// -- WIDE fp16-pair MFMA GEMM: 128x256 tile, 8 waves of 64x64, dbuf 96KB ----
// A planes [M][K], B planes [N][K]; C = A * B^T (+ epilogue).
// Per buffer (shorts): As_h [0,4096) | Bs_h [4096,12288) |
//                      As_l [12288,16384) | Bs_l [16384,24576)
// EPI: 0 = fp32 out+bias (qkv); 1 = gelu -> hi/lo planes (fc1);
//      2 = +bias+resid fp32 (proj)
template <int EPI>
__global__ __launch_bounds__(512) void wgemm(
    const short* __restrict__ Ah, const short* __restrict__ Al,
    const short* __restrict__ Bh, const short* __restrict__ Bl,
    const int K, const float* __restrict__ bias,
    float* __restrict__ outF, short* __restrict__ outH, short* __restrict__ outL,
    const int ldo,
    const float* __restrict__ resid, const int rowOff, const int perm, const int shift) {
  __shared__ short lds[49152];   // 2 x 24576
  const int m0 = blockIdx.x * 128, n0 = blockIdx.y * 256;
  const int t  = threadIdx.x;
  const int wv = t >> 6, ln = t & 63;
  const int wr = (wv >> 2) * 64, wc = (wv & 3) * 64;   // wave tile 64x64
  const int l15 = ln & 15, l4 = ln >> 4;

  f32x4 accH[4][4], accL[4][4];
#pragma unroll
  for (int mf = 0; mf < 4; mf++)
#pragma unroll
    for (int nf = 0; nf < 4; nf++) {
      accH[mf][nf] = (f32x4){0.f, 0.f, 0.f, 0.f};
      accL[mf][nf] = (f32x4){0.f, 0.f, 0.f, 0.f};
    }

  const int srow = ln >> 2;
  const int scol = ((ln & 3) ^ ((ln >> 3) & 3)) * 8;

  auto stage = [&](int buf, int k0) {
    short* b = lds + buf * 24576;
#pragma unroll
    for (int q = 0; q < 6; q++) {
      int s = wv * 6 + q;                 // 0..47
      const short* src; short* dstp; int rowbase;
      if (s < 8)       { src = Ah; dstp = b + s * 512;                rowbase = m0 + s * 16; }
      else if (s < 24) { src = Bh; dstp = b + 4096 + (s - 8) * 512;   rowbase = n0 + (s - 8) * 16; }
      else if (s < 32) { src = Al; dstp = b + 12288 + (s - 24) * 512; rowbase = m0 + (s - 24) * 16; }
      else             { src = Bl; dstp = b + 16384 + (s - 32) * 512; rowbase = n0 + (s - 32) * 16; }
      gload16(src + (size_t)(rowbase + srow) * K + k0 + scol, dstp);
    }
  };
  auto frag = [&](const short* lt, int rbase) -> f16x8 {
    int r = rbase + l15;
    int kc = l4 ^ ((r >> 1) & 3);
    return *(const f16x8*)(lt + (r >> 4) * 512 + (r & 15) * 32 + kc * 8);
  };

  stage(0, 0);
  __syncthreads();
  int cur = 0;
  for (int k0 = 0; k0 < K; k0 += 32) {
    if (k0 + 32 < K) stage(cur ^ 1, k0 + 32);
    const short* b = lds + cur * 24576;
    f16x8 ah[4], bh[4], bl[4];
#pragma unroll
    for (int mf = 0; mf < 4; mf++) ah[mf] = frag(b, wr + mf * 16);
#pragma unroll
    for (int nf = 0; nf < 4; nf++) bh[nf] = frag(b + 4096, wc + nf * 16);
#pragma unroll
    for (int mf = 0; mf < 4; mf++)
#pragma unroll
      for (int nf = 0; nf < 4; nf++)
        accH[mf][nf] = __builtin_amdgcn_mfma_f32_16x16x32_f16(ah[mf], bh[nf], accH[mf][nf], 0, 0, 0);
#pragma unroll
    for (int nf = 0; nf < 4; nf++) bl[nf] = frag(b + 16384, wc + nf * 16);
#pragma unroll
    for (int mf = 0; mf < 4; mf++)
#pragma unroll
      for (int nf = 0; nf < 4; nf++)
        accL[mf][nf] = __builtin_amdgcn_mfma_f32_16x16x32_f16(ah[mf], bl[nf], accL[mf][nf], 0, 0, 0);
#pragma unroll
    for (int mf = 0; mf < 4; mf++) {
      f16x8 al = frag(b + 12288, wr + mf * 16);
#pragma unroll
      for (int nf = 0; nf < 4; nf++)
        accL[mf][nf] = __builtin_amdgcn_mfma_f32_16x16x32_f16(al, bh[nf], accL[mf][nf], 0, 0, 0);
    }
    __syncthreads();
    cur ^= 1;
  }

  f32x4 acc[4][4];
#pragma unroll
  for (int mf = 0; mf < 4; mf++)
#pragma unroll
    for (int nf = 0; nf < 4; nf++)
#pragma unroll
      for (int r = 0; r < 4; r++)
        acc[mf][nf][r] = fmaf(accL[mf][nf][r], LINV, accH[mf][nf][r]);

  if (EPI == 0) {
#pragma unroll
    for (int mf = 0; mf < 4; mf++)
#pragma unroll
      for (int r = 0; r < 4; r++) {
        int row = m0 + wr + mf * 16 + l4 * 4 + r;
        float* op = outF + (size_t)row * ldo;
#pragma unroll
        for (int nf = 0; nf < 4; nf++) {
          int col = n0 + wc + nf * 16 + l15;
          op[col] = acc[mf][nf][r] + bias[col];
        }
      }
  } else if (EPI == 1) {
#pragma unroll
    for (int mf = 0; mf < 4; mf++)
#pragma unroll
      for (int r = 0; r < 4; r++) {
        int row = m0 + wr + mf * 16 + l4 * 4 + r;
#pragma unroll
        for (int nf = 0; nf < 4; nf++) {
          int col = n0 + wc + nf * 16 + l15;
          float v = acc[mf][nf][r] + bias[col];
          v = 0.5f * v * (1.0f + erff(v * 0.70710678118654752f));
          short h, l;
          f2hsplit(v, h, l);
          outH[(size_t)row * ldo + col] = h;
          outL[(size_t)row * ldo + col] = l;
        }
      }
  } else {  // EPI == 2
#pragma unroll
    for (int mf = 0; mf < 4; mf++)
#pragma unroll
      for (int r = 0; r < 4; r++) {
        int row = m0 + wr + mf * 16 + l4 * 4 + r;
        int orow = perm ? rowmap(row, shift) : (row + rowOff);
        const float* rp = resid + (size_t)orow * ldo;
        float* op = outF + (size_t)orow * ldo;
#pragma unroll
        for (int nf = 0; nf < 4; nf++) {
          int col = n0 + wc + nf * 16 + l15;
          op[col] = rp[col] + acc[mf][nf][r] + bias[col];
        }
      }
  }
}

// -- narrow fp16-pair MFMA GEMM, 128x128 tile, BK=32, 8 waves, dbuf ---------
// kept for fc2 (N=512: wide grid would underfill).
// EPI: 2 = +bias+resid fp32; 4 = EPI2 + h/l plane store
template <int EPI>
__global__ __launch_bounds__(512) void mgemm(
    const short* __restrict__ Ah, const short* __restrict__ Al,
    const short* __restrict__ Bh, const short* __restrict__ Bl,
    const int K, const float* __restrict__ bias,
    float* __restrict__ outF, short* __restrict__ outH, short* __restrict__ outL,
    const int ldo,
    const float* __restrict__ resid, const int rowOff, const int perm, const int shift) {
  __shared__ short lds[32768];   // 2 buffers x (Ah|Bh|Al|Bl) 128x32 fp16 tiles
  const int m0 = blockIdx.x * 128, n0 = blockIdx.y * 128;
  const int t  = threadIdx.x;
  const int wv = t >> 6, ln = t & 63;
  const int wr = (wv >> 2) * 64, wc = (wv & 3) * 32;   // wave tile 64x32
  const int l15 = ln & 15, l4 = ln >> 4;

  f32x4 accH[4][2], accL[4][2];
#pragma unroll
  for (int mf = 0; mf < 4; mf++)
#pragma unroll
    for (int nf = 0; nf < 2; nf++) {
      accH[mf][nf] = (f32x4){0.f, 0.f, 0.f, 0.f};
      accL[mf][nf] = (f32x4){0.f, 0.f, 0.f, 0.f};
    }

  const int srow = ln >> 2;
  const int scol = ((ln & 3) ^ ((ln >> 3) & 3)) * 8;

  auto stage = [&](int buf, int k0) {
    short* b = lds + buf * 16384;
    size_t ra = (size_t)(m0 + wv * 16 + srow) * K + k0 + scol;
    size_t rb = (size_t)(n0 + wv * 16 + srow) * K + k0 + scol;
    gload16(Ah + ra, b + wv * 512);
    gload16(Bh + rb, b + 4096 + wv * 512);
    gload16(Al + ra, b + 8192 + wv * 512);
    gload16(Bl + rb, b + 12288 + wv * 512);
  };
  auto frag = [&](const short* lt, int rbase) -> f16x8 {
    int r = rbase + l15;
    int kc = l4 ^ ((r >> 1) & 3);
    return *(const f16x8*)(lt + (r >> 4) * 512 + (r & 15) * 32 + kc * 8);
  };

  stage(0, 0);
  __syncthreads();
  int cur = 0;
  for (int k0 = 0; k0 < K; k0 += 32) {
    if (k0 + 32 < K) stage(cur ^ 1, k0 + 32);
    const short* base = lds + cur * 16384;
    f16x8 ah[4], bh[2], bl[2];
#pragma unroll
    for (int mf = 0; mf < 4; mf++) ah[mf] = frag(base, wr + mf * 16);
#pragma unroll
    for (int nf = 0; nf < 2; nf++) bh[nf] = frag(base + 4096, wc + nf * 16);
#pragma unroll
    for (int mf = 0; mf < 4; mf++)
#pragma unroll
      for (int nf = 0; nf < 2; nf++)
        accH[mf][nf] = __builtin_amdgcn_mfma_f32_16x16x32_f16(ah[mf], bh[nf], accH[mf][nf], 0, 0, 0);
#pragma unroll
    for (int nf = 0; nf < 2; nf++) bl[nf] = frag(base + 12288, wc + nf * 16);
#pragma unroll
    for (int mf = 0; mf < 4; mf++)
#pragma unroll
      for (int nf = 0; nf < 2; nf++)
        accL[mf][nf] = __builtin_amdgcn_mfma_f32_16x16x32_f16(ah[mf], bl[nf], accL[mf][nf], 0, 0, 0);
#pragma unroll
    for (int mf = 0; mf < 4; mf++) {
      f16x8 al = frag(base + 8192, wr + mf * 16);
#pragma unroll
      for (int nf = 0; nf < 2; nf++)
        accL[mf][nf] = __builtin_amdgcn_mfma_f32_16x16x32_f16(al, bh[nf], accL[mf][nf], 0, 0, 0);
    }
    __syncthreads();
    cur ^= 1;
  }

  f32x4 acc[4][2];
#pragma unroll
  for (int mf = 0; mf < 4; mf++)
#pragma unroll
    for (int nf = 0; nf < 2; nf++)
#pragma unroll
      for (int r = 0; r < 4; r++)
        acc[mf][nf][r] = fmaf(accL[mf][nf][r], LINV, accH[mf][nf][r]);

  {  // EPI == 2 or 4
#pragma unroll
    for (int mf = 0; mf < 4; mf++)
#pragma unroll
      for (int r = 0; r < 4; r++) {
        int row = m0 + wr + mf * 16 + l4 * 4 + r;
        int orow = perm ? rowmap(row, shift) : (row + rowOff);
        const float* rp = resid + (size_t)orow * ldo;
        float* op = outF + (size_t)orow * ldo;
#pragma unroll
        for (int nf = 0; nf < 2; nf++) {
          int col = n0 + wc + nf * 16 + l15;
          float v = rp[col] + acc[mf][nf][r] + bias[col];
          op[col] = v;
          if (EPI == 4) {
            short h, l;
            f2hsplit(v, h, l);
            outH[(size_t)orow * ldo + col] = h;
            outL[(size_t)orow * ldo + col] = l;
          }
        }
      }
  }
}

// -- VQ distance GEMM: h*h only, 128x256, 8 waves of 64x64, BK=32, dbuf -----
// top-2 per 256-col tile emitted as packed keys; exact rescore downstream.
__global__ __launch_bounds__(512) void vqgemm(
    const short* __restrict__ Ah, const short* __restrict__ Bh,
    const float* __restrict__ c2, unsigned* __restrict__ pk) {
  __shared__ short lds[24576];   // 2 buffers x (A 8 chunks | B 16 chunks)
  const int bid = blockIdx.x;
  const int xcd = bid & 7, idx = bid >> 3;
  const int m0 = (xcd * 32 + (idx & 31)) * 128;   // m-slab per XCD
  const int ny = idx >> 5;                        // 0..15
  const int n0 = ny * 256;
  const int K = 512;
  const int t  = threadIdx.x;
  const int wv = t >> 6, ln = t & 63;
  const int wr = (wv >> 2) * 64, wc = (wv & 3) * 64;  // wave tile 64x64
  const int l15 = ln & 15, l4 = ln >> 4;

  f32x4 acc[4][4];
#pragma unroll
  for (int mf = 0; mf < 4; mf++)
#pragma unroll
    for (int nf = 0; nf < 4; nf++) acc[mf][nf] = (f32x4){0.f, 0.f, 0.f, 0.f};

  const int srow = ln >> 2;
  const int scol = ((ln & 3) ^ ((ln >> 3) & 3)) * 8;

  auto stage = [&](int buf, int k0) {
    short* b = lds + buf * 12288;
#pragma unroll
    for (int q = 0; q < 3; q++) {
      int s = wv * 3 + q;                 // 0..23: 8 A chunks then 16 B chunks
      int isA = (s < 8);
      int c = isA ? s : (s - 8);
      const short* src = isA ? Ah : Bh;
      short* dst = b + (isA ? c * 512 : 4096 + c * 512);
      int rowbase = (isA ? m0 : n0) + c * 16;
      gload16(src + (size_t)(rowbase + srow) * K + k0 + scol, dst);
    }
  };
  auto frag = [&](const short* lt, int rbase) -> f16x8 {
    int r = rbase + l15;
    int kc = l4 ^ ((r >> 1) & 3);
    return *(const f16x8*)(lt + (r >> 4) * 512 + (r & 15) * 32 + kc * 8);
  };

  stage(0, 0);
  __syncthreads();
  int cur = 0;
  for (int k0 = 0; k0 < K; k0 += 32) {
    if (k0 + 32 < K) stage(cur ^ 1, k0 + 32);
    const short* b = lds + cur * 12288;
    f16x8 ah[4], bh[4];
#pragma unroll
    for (int mf = 0; mf < 4; mf++) ah[mf] = frag(b, wr + mf * 16);
#pragma unroll
    for (int nf = 0; nf < 4; nf++) bh[nf] = frag(b + 4096, wc + nf * 16);
#pragma unroll
    for (int mf = 0; mf < 4; mf++)
#pragma unroll
      for (int nf = 0; nf < 4; nf++)
        acc[mf][nf] = __builtin_amdgcn_mfma_f32_16x16x32_f16(ah[mf], bh[nf], acc[mf][nf], 0, 0, 0);
    __syncthreads();
    cur ^= 1;
  }

  // top-2 per row over this 256-col tile
  unsigned* hk = (unsigned*)(void*)lds;   // [128 rows][4 nwaves][2] = 4 KB
#pragma unroll
  for (int mf = 0; mf < 4; mf++)
#pragma unroll
    for (int r = 0; r < 4; r++) {
      int wrow = wr + mf * 16 + l4 * 4 + r;
      unsigned k1 = 0xFFFFFFFFu, k2 = 0xFFFFFFFFu;
#pragma unroll
      for (int nf = 0; nf < 4; nf++) {
        int col = n0 + wc + nf * 16 + l15;
        float d = c2[col] - 2.0f * acc[mf][nf][r];
        unsigned kk = packkey(d, col);
        if (kk < k1) { k2 = k1; k1 = kk; }
        else if (kk < k2) { k2 = kk; }
      }
      // 16-lane (same l4 = same row) top-2 butterfly over the wave's 64 cols
#pragma unroll
      for (int o = 1; o <= 8; o <<= 1) {
        unsigned b1 = (unsigned)__shfl_xor((int)k1, o);
        unsigned b2 = (unsigned)__shfl_xor((int)k2, o);
        unsigned m1 = umn(k1, b1);
        unsigned m2 = umn(umx(k1, b1), umn(k2, b2));
        k1 = m1; k2 = m2;
      }
      if (l15 == 0) {
        hk[wrow * 8 + (wv & 3) * 2 + 0] = k1;
        hk[wrow * 8 + (wv & 3) * 2 + 1] = k2;
      }
    }
  __syncthreads();
  if (t < 128) {
    unsigned q1[4], q2[4];
#pragma unroll
    for (int i = 0; i < 4; i++) {
      q1[i] = hk[t * 8 + i * 2];
      q2[i] = hk[t * 8 + i * 2 + 1];
    }
    unsigned a1 = umn(q1[0], q1[1]);
    unsigned a2 = umn(umx(q1[0], q1[1]), umn(q2[0], q2[1]));
    unsigned b1 = umn(q1[2], q1[3]);
    unsigned b2 = umn(umx(q1[2], q1[3]), umn(q2[2], q2[3]));
    unsigned m1 = umn(a1, b1);
    unsigned m2 = umn(umx(a1, b1), umn(a2, b2));
    size_t base = (size_t)(m0 + t) * 32 + ny * 2;
    pk[base + 0] = m1;
    pk[base + 1] = m2;
  }
}

// ---------------- candidate select + exact fp32 rescore + gather -----------
__global__ __launch_bounds__(256) void vq_out_kernel(
    const unsigned* __restrict__ pk, const float* __restrict__ x,
    const float* __restrict__ cb,
    float* __restrict__ outq, float* __restrict__ outidx) {
  int r = blockIdx.x * 4 + (threadIdx.x >> 6);
  int lane = threadIdx.x & 63;
  unsigned key = (lane < 32) ? pk[(size_t)r * 32 + lane] : 0xFFFFFFFFu;
  unsigned kmin = key;
#pragma unroll
  for (int o = 32; o >= 1; o >>= 1) kmin = umn(kmin, (unsigned)__shfl_xor((int)kmin, o));
  float dmin = unpackd(kmin);
  unsigned long long mask = __ballot(lane < 32 && unpackd(key) <= dmin + 2.0f);

  const float* xr = x + (size_t)r * C + lane * 8;
  float4 xa = *(const float4*)xr;
  float4 xb = *(const float4*)(xr + 4);

  float bestd = 3.4e38f;
  int   besti = 0x7fffffff;
  while (mask) {
    int l = __ffsll(mask) - 1;
    mask &= mask - 1;
    int col = ((unsigned)__shfl((int)key, l)) & 0xFFFu;
    const float* cr = cb + (size_t)col * C + lane * 8;
    float4 ca = *(const float4*)cr;
    float4 cb4 = *(const float4*)(cr + 4);
    float s = 0.f;
    s = fmaf(ca.x, ca.x - 2.f * xa.x, s);
    s = fmaf(ca.y, ca.y - 2.f * xa.y, s);
    s = fmaf(ca.z, ca.z - 2.f * xa.z, s);
    s = fmaf(ca.w, ca.w - 2.f * xa.w, s);
    s = fmaf(cb4.x, cb4.x - 2.f * xb.x, s);
    s = fmaf(cb4.y, cb4.y - 2.f * xb.y, s);
    s = fmaf(cb4.z, cb4.z - 2.f * xb.z, s);
    s = fmaf(cb4.w, cb4.w - 2.f * xb.w, s);
#pragma unroll
    for (int o = 32; o >= 1; o >>= 1) s += __shfl_xor(s, o);
    if (s < bestd || (s == bestd && col < besti)) { bestd = s; besti = col; }
  }
  const float4* src = (const float4*)(cb + (size_t)besti * C + lane * 8);
  float4*       dst = (float4*)(outq + (size_t)r * C + lane * 8);
  dst[0] = src[0];
  dst[1] = src[1];
  if (lane == 0) outidx[r] = (float)besti;
}

// ---------------- fused per-(window, head) attention (fp32) ----------------
__global__ __launch_bounds__(256) void attn_kernel(
    const float* __restrict__ qkv,   // chunk-local windowed rows x 1536
    const float* __restrict__ rpb,   // (225, 8)
    short* __restrict__ Hout, short* __restrict__ Lout,  // global windowed rows x 512
    int winOff, int shift) {
  int wl = blockIdx.x;
  int h  = blockIdx.y;
  int t  = threadIdx.x;
  __shared__ float q[64][64], k[64][64], v[64][64], pT[64][64];

  const float* base = qkv + (size_t)wl * 64 * 1536 + h * 64;
#pragma unroll
  for (int rep = 0; rep < 4; rep++) {
    int f = t + rep * 256;
    int i = f >> 4, dq = (f & 15) * 4;
    const float* rowp = base + (size_t)i * 1536 + dq;
    float4 qv = *(const float4*)(rowp);
    float4 kv = *(const float4*)(rowp + 512);
    float4 vv = *(const float4*)(rowp + 1024);
    q[i][dq] = qv.x * 0.125f; q[i][dq + 1] = qv.y * 0.125f;
    q[i][dq + 2] = qv.z * 0.125f; q[i][dq + 3] = qv.w * 0.125f;
    *(float4*)&k[i][dq] = kv;
    *(float4*)&v[i][dq] = vv;
  }
  __syncthreads();

  int i  = t >> 2;
  int jg = t & 3;
  int wim = (winOff + wl) & 15;
  int wy = wim >> 2, wx = wim & 3;
  int iy = i >> 3, ix = i & 7;

  float qreg[64];
#pragma unroll
  for (int d = 0; d < 64; d += 4) *(float4*)&qreg[d] = *(float4*)&q[i][d];

  int ci = 0;
  if (shift) ci = region(wy * 8 + iy) * 3 + region(wx * 8 + ix);

  float sc[16];
#pragma unroll
  for (int jj = 0; jj < 16; jj++) {
    int j = jg * 16 + jj;
    float s = 0.f;
#pragma unroll
    for (int d = 0; d < 64; d += 4) {
      float4 kv = *(float4*)&k[j][d];
      s = fmaf(qreg[d], kv.x, s);
      s = fmaf(qreg[d + 1], kv.y, s);
      s = fmaf(qreg[d + 2], kv.z, s);
      s = fmaf(qreg[d + 3], kv.w, s);
    }
    int jy = j >> 3, jx = j & 7;
    s += rpb[((iy - jy + 7) * 15 + (ix - jx + 7)) * 8 + h];
    if (shift) {
      int cj = region(wy * 8 + jy) * 3 + region(wx * 8 + jx);
      if (ci != cj) s -= 100.0f;
    }
    sc[jj] = s;
  }
  float mx = sc[0];
#pragma unroll
  for (int jj = 1; jj < 16; jj++) mx = fmaxf(mx, sc[jj]);
  mx = fmaxf(mx, __shfl_xor(mx, 1));
  mx = fmaxf(mx, __shfl_xor(mx, 2));
  float sum = 0.f;
#pragma unroll
  for (int jj = 0; jj < 16; jj++) { sc[jj] = expf(sc[jj] - mx); sum += sc[jj]; }
  sum += __shfl_xor(sum, 1);
  sum += __shfl_xor(sum, 2);
  float inv = 1.0f / sum;
#pragma unroll
  for (int jj = 0; jj < 16; jj++) pT[jg * 16 + jj][i] = sc[jj] * inv;
  __syncthreads();

  float accv[16];
#pragma unroll
  for (int dd = 0; dd < 16; dd++) accv[dd] = 0.f;
  for (int j = 0; j < 64; j++) {
    float pij = pT[j][i];
#pragma unroll
    for (int dd = 0; dd < 16; dd += 4) {
      float4 vv = *(float4*)&v[j][jg * 16 + dd];
      accv[dd]     = fmaf(pij, vv.x, accv[dd]);
      accv[dd + 1] = fmaf(pij, vv.y, accv[dd + 1]);
      accv[dd + 2] = fmaf(pij, vv.z, accv[dd + 2]);
      accv[dd + 3] = fmaf(pij, vv.w, accv[dd + 3]);
    }
  }
  size_t obase = ((size_t)(winOff + wl) * 64 + i) * 512 + h * 64 + jg * 16;
  short8 hv, lv;
#pragma unroll
  for (int half = 0; half < 2; half++) {
#pragma unroll
    for (int j = 0; j < 8; j++) {
      short hh, ll;
      f2hsplit(accv[half * 8 + j], hh, ll);
      hv[j] = hh; lv[j] = ll;
    }
    *(short8*)&Hout[obase + half * 8] = hv;
    *(short8*)&Lout[obase + half * 8] = lv;
  }
}

}  // namespace

extern "C" void kernel_launch(void* const* d_in, const int* in_sizes, int n_in,
                              void* d_out, int out_size, void* d_ws, size_t ws_size,
                              hipStream_t stream) {
  const float* x_in = (const float*)d_in[0];
  const float* n1g  = (const float*)d_in[1];
  const float* n1b  = (const float*)d_in[2];
  const float* qkvw = (const float*)d_in[3];
  const float* qkvb = (const float*)d_in[4];
  const float* rpb  = (const float*)d_in[5];
  const float* pw   = (const float*)d_in[6];
  const float* pb   = (const float*)d_in[7];
  const float* n2g  = (const float*)d_in[8];
  const float* n2b  = (const float*)d_in[9];
  const float* f1w  = (const float*)d_in[10];
  const float* f1b  = (const float*)d_in[11];
  const float* f2w  = (const float*)d_in[12];
  const float* f2b_ = (const float*)d_in[13];
  const float* cb   = (const float*)d_in[14];

  float* outq   = (float*)d_out;
  float* outidx = outq + 16777216;
  short* Hbuf = (short*)d_out;                 // hi plane: first 32MB of outq
  short* Lbuf = Hbuf + (size_t)ROWS * 512;     // lo plane: second 32MB

  char* ws = (char*)d_ws;
  float* Abuf = (float*)ws;                               // 64MiB residual stream
  short* Wb   = (short*)(ws + ((size_t)64 << 20));        // 32MiB weight planes
  char*  Cbuf = ws + ((size_t)96 << 20);                  // chunk scratch
  const int Rrows = (ws_size >= ((size_t)232 << 20)) ? 16384
                  : (ws_size >= ((size_t)160 << 20)) ? 8192
                  : (ws_size >= ((size_t)128 << 20)) ? 4096 : 2048;

  const int SZ_QKV = 512 * 1536, SZ_P = 512 * 512, SZ_F1 = 512 * 2048, SZ_F2 = 2048 * 512;
  const int PB = (SZ_QKV + SZ_P + SZ_F1 + SZ_F2) * 2;
  short* cbH = Wb + (size_t)2 * PB;
  short* cbL = cbH + 4096 * 512;

  // ---- one-time (per launch) weight transpose + split ----
  for (int blk = 0; blk < 2; blk++) {
    short* base = Wb + (size_t)blk * PB;
    short* qH = base;          short* qL = qH + SZ_QKV;
    short* pH = qL + SZ_QKV;   short* pL = pH + SZ_P;
    short* f1H = pL + SZ_P;    short* f1L = f1H + SZ_F1;
    short* f2H = f1L + SZ_F1;  short* f2L = f2H + SZ_F2;
    wconvT_kernel<<<dim3(48, 16), dim3(32, 8), 0, stream>>>(qkvw + (size_t)blk * SZ_QKV, qH, qL, 512, 1536);
    wconvT_kernel<<<dim3(16, 16), dim3(32, 8), 0, stream>>>(pw + (size_t)blk * SZ_P, pH, pL, 512, 512);
    wconvT_kernel<<<dim3(64, 16), dim3(32, 8), 0, stream>>>(f1w + (size_t)blk * SZ_F1, f1H, f1L, 512, 2048);
    wconvT_kernel<<<dim3(16, 64), dim3(32, 8), 0, stream>>>(f2w + (size_t)blk * SZ_F2, f2H, f2L, 2048, 512);
  }
  wconv_kernel<<<2048, 256, 0, stream>>>(cb, cbH, cbL);

  const int nch = ROWS / Rrows;
  for (int blk = 0; blk < 2; blk++) {
    short* base = Wb + (size_t)blk * PB;
    short* qH = base;          short* qL = qH + SZ_QKV;
    short* pH = qL + SZ_QKV;   short* pL = pH + SZ_P;
    short* f1H = pL + SZ_P;    short* f1L = f1H + SZ_F1;
    short* f2H = f1L + SZ_F1;  short* f2L = f2H + SZ_F2;
    const float* xcur = blk ? (const float*)Abuf : x_in;
    int shift = blk ? 4 : 0;

    // LN1 + shift + window partition -> hi/lo planes (windowed order)
    ln_split_kernel<<<8192, 256, 0, stream>>>(xcur, Hbuf, Lbuf, n1g + blk * 512, n1b + blk * 512, shift, 1);

    // qkv GEMM (fp32 out) + attention (writes planes back in place)
    float* Cq = (float*)Cbuf;
    for (int ch = 0; ch < nch; ch++) {
      int r0 = ch * Rrows;
      wgemm<0><<<dim3(Rrows / 128, 6), 512, 0, stream>>>(
          Hbuf + (size_t)r0 * 512, Lbuf + (size_t)r0 * 512, qH, qL, 512,
          qkvb + blk * 1536, Cq, nullptr, nullptr, 1536,
          nullptr, 0, 0, 0);
      attn_kernel<<<dim3(Rrows / 64, 8), 256, 0, stream>>>(
          Cq, rpb + blk * 1800, Hbuf, Lbuf, r0 >> 6, shift);
    }

    // proj + window reverse + unshift + residual -> Abuf (fp32), full M
    wgemm<2><<<dim3(256, 2), 512, 0, stream>>>(
        Hbuf, Lbuf, pH, pL, 512, pb + blk * 512,
        Abuf, nullptr, nullptr, 512,
        blk ? (const float*)Abuf : x_in, 0, 1, shift);

    // LN2 -> planes (identity order)
    ln_split_kernel<<<8192, 256, 0, stream>>>(Abuf, Hbuf, Lbuf, n2g + blk * 512, n2b + blk * 512, 0, 0);

    // MLP; blk==1 fc2 also emits h/l planes (fused split for VQ)
    short* gh = (short*)Cbuf;
    short* gl = gh + (size_t)Rrows * 2048;
    for (int ch = 0; ch < nch; ch++) {
      int r0 = ch * Rrows;
      wgemm<1><<<dim3(Rrows / 128, 8), 512, 0, stream>>>(
          Hbuf + (size_t)r0 * 512, Lbuf + (size_t)r0 * 512, f1H, f1L, 512,
          f1b + blk * 2048, nullptr, gh, gl, 2048,
          nullptr, 0, 0, 0);
      if (blk == 0) {
        mgemm<2><<<dim3(Rrows / 128, 4), 512, 0, stream>>>(
            gh, gl, f2H, f2L, 2048, f2b_ + blk * 512,
            Abuf, nullptr, nullptr, 512,
            Abuf, r0, 0, 0);
      } else {
        mgemm<4><<<dim3(Rrows / 128, 4), 512, 0, stream>>>(
            gh, gl, f2H, f2L, 2048, f2b_ + blk * 512,
            Abuf, Hbuf, Lbuf, 512,
            Abuf, r0, 0, 0);
      }
    }
  }

  // ---- VQ: approx top-2/tile via single-pass fp16 GEMM, exact rescore ----
  float*    c2  = (float*)Cbuf;                              // 16 KB
  unsigned* pkb = (unsigned*)(Cbuf + ((size_t)64 << 10));    // 4 MiB: 32768 x 32 keys
  rowss_kernel<<<1024, 256, 0, stream>>>(cb, c2, 4096);
  vqgemm<<<4096, 512, 0, stream>>>(Hbuf, cbH, c2, pkb);
  vq_out_kernel<<<8192, 256, 0, stream>>>(pkb, Abuf, cb, outq, outidx);
}

// Round 12
// 2290.341 us; speedup vs baseline: 1.1892x; 1.1892x over previous
//
#include <hip/hip_runtime.h>
#include <math.h>

#define DEV __device__ __forceinline__

typedef __attribute__((ext_vector_type(8))) _Float16 f16x8;
typedef __attribute__((ext_vector_type(8))) short short8;
typedef __attribute__((ext_vector_type(4))) float f32x4;

namespace {

constexpr int C = 512;
constexpr int ROWS = 32768;   // B * L
constexpr float LSCALE = 2048.0f;        // lo-plane pre-scale (2^11)
constexpr float LINV   = 1.0f / 2048.0f;
constexpr float F16MIN = 6.1035156e-5f;  // fp16 min normal

// fp32 -> fp16 hi/lo split. h = RTN(x) (flushed to 0 below normal range),
// l = RTN((x - h) * 2^11). Ensures all MFMA inputs are 0 or normal fp16.
DEV void f2hsplit(float x, short& hs, short& ls) {
  _Float16 h = (_Float16)x;
  float hf = (float)h;
  if (fabsf(hf) < F16MIN) { h = (_Float16)0.0f; hf = 0.f; }
  _Float16 l = (_Float16)((x - hf) * LSCALE);
  if (fabsf((float)l) < F16MIN) l = (_Float16)0.0f;
  hs = __builtin_bit_cast(short, h);
  ls = __builtin_bit_cast(short, l);
}

DEV unsigned umn(unsigned a, unsigned b) { return a < b ? a : b; }
DEV unsigned umx(unsigned a, unsigned b) { return a > b ? a : b; }

// monotone key: high 20 bits = sign-flipped fp32 distance, low 12 = col idx.
DEV unsigned packkey(float d, int col) {
  unsigned u = __builtin_bit_cast(unsigned, d);
  u = (u & 0x80000000u) ? ~u : (u | 0x80000000u);
  return (u & 0xFFFFF000u) | (unsigned)col;
}
DEV float unpackd(unsigned k) {
  unsigned u = (k & 0x80000000u) ? (k ^ 0x80000000u) : ~k;
  return __builtin_bit_cast(float, u);
}

// windowed row r -> flat row in (b, y, x) order, for roll by `shift`.
DEV int rowmap(int r, int shift) {
  int b  = r >> 10;
  int w  = (r >> 6) & 15;
  int wy = w >> 2, wx = w & 3;
  int ii = r & 63;
  int iy = ii >> 3, ix = ii & 7;
  int y = (wy * 8 + iy + shift) & 31;
  int x = (wx * 8 + ix + shift) & 31;
  return (b << 10) + (y << 5) + x;
}

DEV int region(int y) { return (y < 24) ? 0 : ((y < 28) ? 1 : 2); }

typedef __attribute__((address_space(1))) const unsigned int gu32;
typedef __attribute__((address_space(3))) unsigned int lu32;
DEV void gload16(const void* g, void* l) {
  __builtin_amdgcn_global_load_lds((gu32*)g, (lu32*)l, 16, 0, 0);
}

// ---------------- LayerNorm -> fp16 hi/lo planes ---------------------------
__global__ __launch_bounds__(256) void ln_split_kernel(
    const float* __restrict__ src, short* __restrict__ Hp, short* __restrict__ Lp,
    const float* __restrict__ g, const float* __restrict__ b,
    int shift, int windowed) {
  int wid  = (blockIdx.x * 256 + threadIdx.x) >> 6;
  int lane = threadIdx.x & 63;
  if (wid >= ROWS) return;
  int srcRow = windowed ? rowmap(wid, shift) : wid;
  const float* s = src + (size_t)srcRow * C + lane * 8;
  float v[8];
  *(float4*)(v)     = *(const float4*)(s);
  *(float4*)(v + 4) = *(const float4*)(s + 4);
  float sum = 0.f;
#pragma unroll
  for (int j = 0; j < 8; j++) sum += v[j];
#pragma unroll
  for (int o = 32; o >= 1; o >>= 1) sum += __shfl_xor(sum, o);
  float mu = sum * (1.0f / 512.0f);
  float vs = 0.f;
#pragma unroll
  for (int j = 0; j < 8; j++) { float d = v[j] - mu; vs += d * d; }
#pragma unroll
  for (int o = 32; o >= 1; o >>= 1) vs += __shfl_xor(vs, o);
  float rs = rsqrtf(vs * (1.0f / 512.0f) + 1e-5f);
  float gg[8], bb[8];
  *(float4*)gg       = *(const float4*)&g[lane * 8];
  *(float4*)(gg + 4) = *(const float4*)&g[lane * 8 + 4];
  *(float4*)bb       = *(const float4*)&b[lane * 8];
  *(float4*)(bb + 4) = *(const float4*)&b[lane * 8 + 4];
  short8 hv, lv;
#pragma unroll
  for (int j = 0; j < 8; j++) {
    float o8 = (v[j] - mu) * rs * gg[j] + bb[j];
    short hh, ll;
    f2hsplit(o8, hh, ll);
    hv[j] = hh; lv[j] = ll;
  }
  *(short8*)&Hp[(size_t)wid * C + lane * 8] = hv;
  *(short8*)&Lp[(size_t)wid * C + lane * 8] = lv;
}

// ---------------- row sum of squares (codebook) ----------------------------
__global__ __launch_bounds__(256) void rowss_kernel(
    const float* __restrict__ src, float* __restrict__ dst, int nrows) {
  int wid  = (blockIdx.x * 256 + threadIdx.x) >> 6;
  int lane = threadIdx.x & 63;
  if (wid >= nrows) return;
  const float* s = src + (size_t)wid * C + lane * 8;
  float4 a  = *(const float4*)s;
  float4 b4 = *(const float4*)(s + 4);
  float sum = a.x*a.x + a.y*a.y + a.z*a.z + a.w*a.w
            + b4.x*b4.x + b4.y*b4.y + b4.z*b4.z + b4.w*b4.w;
#pragma unroll
  for (int o = 32; o >= 1; o >>= 1) sum += __shfl_xor(sum, o);
  if (lane == 0) dst[wid] = sum;
}

// ---------------- weight transpose + split: W(K,N) -> H/L (N,K) ------------
__global__ __launch_bounds__(256) void wconvT_kernel(
    const float* __restrict__ W, short* __restrict__ Hp, short* __restrict__ Lp,
    int K, int N) {
  __shared__ float t[32][33];
  int tx = threadIdx.x, ty = threadIdx.y;
  int n0 = blockIdx.x * 32, k0 = blockIdx.y * 32;
#pragma unroll
  for (int r = 0; r < 4; r++) {
    int k = ty + r * 8;
    t[k][tx] = W[(size_t)(k0 + k) * N + n0 + tx];
  }
  __syncthreads();
#pragma unroll
  for (int r = 0; r < 4; r++) {
    int n = ty + r * 8;
    short h, l;
    f2hsplit(t[tx][n], h, l);
    Hp[(size_t)(n0 + n) * K + k0 + tx] = h;
    Lp[(size_t)(n0 + n) * K + k0 + tx] = l;
  }
}

// ---------------- codebook split (already N-major) -------------------------
__global__ __launch_bounds__(256) void wconv_kernel(
    const float* __restrict__ W, short* __restrict__ Hp, short* __restrict__ Lp) {
  size_t i = ((size_t)blockIdx.x * 256 + threadIdx.x) * 4;
  float4 a = *(const float4*)&W[i];
  float v[4] = {a.x, a.y, a.z, a.w};
  short hv[4], lv[4];
#pragma unroll
  for (int j = 0; j < 4; j++) f2hsplit(v[j], hv[j], lv[j]);
  *(short4*)&Hp[i] = *(short4*)hv;
  *(short4*)&Lp[i] = *(short4*)lv;
}

// -- fp16-pair MFMA GEMM, 128x128 tile, BK=32, 8 waves, LDS double-buffer ---
// A planes [M][K], B planes [N][K]; C = A * B^T (+ epilogue).
// acc = accH(h*h) + 2^-11 * accL(h*lw + la*h); la/lw are pre-scaled by 2^11.
// EPI: 0 = fp32 out+bias (qkv); 1 = gelu -> hi/lo planes (fc1);
//      2 = +bias+resid fp32 (proj/fc2); 4 = EPI2 + h/l plane store
template <int EPI>
__global__ __launch_bounds__(512) void mgemm(
    const short* __restrict__ Ah, const short* __restrict__ Al,
    const short* __restrict__ Bh, const short* __restrict__ Bl,
    const int K, const float* __restrict__ bias,
    float* __restrict__ outF, short* __restrict__ outH, short* __restrict__ outL,
    const int ldo,
    const float* __restrict__ resid, const int rowOff, const int perm, const int shift) {
  __shared__ short lds[32768];   // 2 buffers x (Ah|Bh|Al|Bl) 128x32 fp16 tiles
  const int m0 = blockIdx.x * 128, n0 = blockIdx.y * 128;
  const int t  = threadIdx.x;
  const int wv = t >> 6, ln = t & 63;
  const int wr = (wv >> 2) * 64, wc = (wv & 3) * 32;   // wave tile 64x32
  const int l15 = ln & 15, l4 = ln >> 4;

  f32x4 accH[4][2], accL[4][2];
#pragma unroll
  for (int mf = 0; mf < 4; mf++)
#pragma unroll
    for (int nf = 0; nf < 2; nf++) {
      accH[mf][nf] = (f32x4){0.f, 0.f, 0.f, 0.f};
      accL[mf][nf] = (f32x4){0.f, 0.f, 0.f, 0.f};
    }

  const int srow = ln >> 2;
  const int scol = ((ln & 3) ^ ((ln >> 3) & 3)) * 8;

  auto stage = [&](int buf, int k0) {
    short* b = lds + buf * 16384;
    size_t ra = (size_t)(m0 + wv * 16 + srow) * K + k0 + scol;
    size_t rb = (size_t)(n0 + wv * 16 + srow) * K + k0 + scol;
    gload16(Ah + ra, b + wv * 512);
    gload16(Bh + rb, b + 4096 + wv * 512);
    gload16(Al + ra, b + 8192 + wv * 512);
    gload16(Bl + rb, b + 12288 + wv * 512);
  };
  auto frag = [&](const short* lt, int rbase) -> f16x8 {
    int r = rbase + l15;
    int kc = l4 ^ ((r >> 1) & 3);
    return *(const f16x8*)(lt + (r >> 4) * 512 + (r & 15) * 32 + kc * 8);
  };

  stage(0, 0);
  __syncthreads();
  int cur = 0;
  for (int k0 = 0; k0 < K; k0 += 32) {
    if (k0 + 32 < K) stage(cur ^ 1, k0 + 32);
    const short* base = lds + cur * 16384;
    f16x8 ah[4], bh[2], bl[2];
#pragma unroll
    for (int mf = 0; mf < 4; mf++) ah[mf] = frag(base, wr + mf * 16);
#pragma unroll
    for (int nf = 0; nf < 2; nf++) bh[nf] = frag(base + 4096, wc + nf * 16);
    __builtin_amdgcn_s_setprio(1);
#pragma unroll
    for (int mf = 0; mf < 4; mf++)
#pragma unroll
      for (int nf = 0; nf < 2; nf++)
        accH[mf][nf] = __builtin_amdgcn_mfma_f32_16x16x32_f16(ah[mf], bh[nf], accH[mf][nf], 0, 0, 0);
    __builtin_amdgcn_s_setprio(0);
#pragma unroll
    for (int nf = 0; nf < 2; nf++) bl[nf] = frag(base + 12288, wc + nf * 16);
    __builtin_amdgcn_s_setprio(1);
#pragma unroll
    for (int mf = 0; mf < 4; mf++)
#pragma unroll
      for (int nf = 0; nf < 2; nf++)
        accL[mf][nf] = __builtin_amdgcn_mfma_f32_16x16x32_f16(ah[mf], bl[nf], accL[mf][nf], 0, 0, 0);
#pragma unroll
    for (int mf = 0; mf < 4; mf++) {
      f16x8 al = frag(base + 8192, wr + mf * 16);
#pragma unroll
      for (int nf = 0; nf < 2; nf++)
        accL[mf][nf] = __builtin_amdgcn_mfma_f32_16x16x32_f16(al, bh[nf], accL[mf][nf], 0, 0, 0);
    }
    __builtin_amdgcn_s_setprio(0);
    __syncthreads();
    cur ^= 1;
  }

  f32x4 acc[4][2];
#pragma unroll
  for (int mf = 0; mf < 4; mf++)
#pragma unroll
    for (int nf = 0; nf < 2; nf++)
#pragma unroll
      for (int r = 0; r < 4; r++)
        acc[mf][nf][r] = fmaf(accL[mf][nf][r], LINV, accH[mf][nf][r]);

  if (EPI == 0) {
#pragma unroll
    for (int mf = 0; mf < 4; mf++)
#pragma unroll
      for (int r = 0; r < 4; r++) {
        int row = m0 + wr + mf * 16 + l4 * 4 + r;
        float* op = outF + (size_t)row * ldo;
#pragma unroll
        for (int nf = 0; nf < 2; nf++) {
          int col = n0 + wc + nf * 16 + l15;
          op[col] = acc[mf][nf][r] + bias[col];
        }
      }
  } else if (EPI == 1) {
#pragma unroll
    for (int mf = 0; mf < 4; mf++)
#pragma unroll
      for (int r = 0; r < 4; r++) {
        int row = m0 + wr + mf * 16 + l4 * 4 + r;
#pragma unroll
        for (int nf = 0; nf < 2; nf++) {
          int col = n0 + wc + nf * 16 + l15;
          float v = acc[mf][nf][r] + bias[col];
          v = 0.5f * v * (1.0f + erff(v * 0.70710678118654752f));
          short h, l;
          f2hsplit(v, h, l);
          outH[(size_t)row * ldo + col] = h;
          outL[(size_t)row * ldo + col] = l;
        }
      }
  } else {  // EPI == 2 or 4
#pragma unroll
    for (int mf = 0; mf < 4; mf++)
#pragma unroll
      for (int r = 0; r < 4; r++) {
        int row = m0 + wr + mf * 16 + l4 * 4 + r;
        int orow = perm ? rowmap(row, shift) : (row + rowOff);
        const float* rp = resid + (size_t)orow * ldo;
        float* op = outF + (size_t)orow * ldo;
#pragma unroll
        for (int nf = 0; nf < 2; nf++) {
          int col = n0 + wc + nf * 16 + l15;
          float v = rp[col] + acc[mf][nf][r] + bias[col];
          op[col] = v;
          if (EPI == 4) {
            short h, l;
            f2hsplit(v, h, l);
            outH[(size_t)orow * ldo + col] = h;
            outL[(size_t)orow * ldo + col] = l;
          }
        }
      }
  }
}

// -- VQ distance GEMM: h*h only, block 128x256, 8 waves of 64x64, BK=32 -----
// 4x4 fragment reuse: 8 frag reads per 16 MFMA. Single-buffer, 2 barriers.
// top-2 per 256-col tile emitted as packed keys; exact rescore downstream.
__global__ __launch_bounds__(512) void vqgemm(
    const short* __restrict__ Ah, const short* __restrict__ Bh,
    const float* __restrict__ c2, unsigned* __restrict__ pk) {
  __shared__ short lds[12288];   // A 128x32 (8 chunks) | B 256x32 (16 chunks)
  const int bid = blockIdx.x;
  const int xcd = bid & 7, idx = bid >> 3;
  const int m0 = (xcd * 32 + (idx & 31)) * 128;   // m-slab per XCD
  const int ny = idx >> 5;                        // 0..15
  const int n0 = ny * 256;
  const int K = 512;
  const int t  = threadIdx.x;
  const int wv = t >> 6, ln = t & 63;
  const int wr = (wv >> 2) * 64, wc = (wv & 3) * 64;  // wave tile 64x64
  const int l15 = ln & 15, l4 = ln >> 4;

  f32x4 acc[4][4];
#pragma unroll
  for (int mf = 0; mf < 4; mf++)
#pragma unroll
    for (int nf = 0; nf < 4; nf++) acc[mf][nf] = (f32x4){0.f, 0.f, 0.f, 0.f};

  const int srow = ln >> 2;
  const int scol = ((ln & 3) ^ ((ln >> 3) & 3)) * 8;

  short* As = lds;            // 8 chunks
  short* Bs = lds + 4096;     // 16 chunks

  auto frag = [&](const short* lt, int rbase) -> f16x8 {
    int r = rbase + l15;
    int kc = l4 ^ ((r >> 1) & 3);
    return *(const f16x8*)(lt + (r >> 4) * 512 + (r & 15) * 32 + kc * 8);
  };

  for (int k0 = 0; k0 < K; k0 += 32) {
#pragma unroll
    for (int q = 0; q < 3; q++) {
      int s = wv * 3 + q;                 // 0..23: 8 A chunks then 16 B chunks
      int isA = (s < 8);
      int c = isA ? s : (s - 8);
      const short* src = isA ? Ah : Bh;
      short* dst = (isA ? As : Bs) + c * 512;
      int rowbase = (isA ? m0 : n0) + c * 16;
      size_t ga = (size_t)(rowbase + srow) * K + k0 + scol;
      gload16(src + ga, dst);
    }
    __syncthreads();
    f16x8 ah[4], bh[4];
#pragma unroll
    for (int mf = 0; mf < 4; mf++) ah[mf] = frag(As, wr + mf * 16);
#pragma unroll
    for (int nf = 0; nf < 4; nf++) bh[nf] = frag(Bs, wc + nf * 16);
    __builtin_amdgcn_s_setprio(1);
#pragma unroll
    for (int mf = 0; mf < 4; mf++)
#pragma unroll
      for (int nf = 0; nf < 4; nf++)
        acc[mf][nf] = __builtin_amdgcn_mfma_f32_16x16x32_f16(ah[mf], bh[nf], acc[mf][nf], 0, 0, 0);
    __builtin_amdgcn_s_setprio(0);
    __syncthreads();
  }

  // top-2 per row over this 256-col tile
  unsigned* hk = (unsigned*)(void*)lds;   // [128 rows][4 nwaves][2] = 4 KB
#pragma unroll
  for (int mf = 0; mf < 4; mf++)
#pragma unroll
    for (int r = 0; r < 4; r++) {
      int wrow = wr + mf * 16 + l4 * 4 + r;
      unsigned k1 = 0xFFFFFFFFu, k2 = 0xFFFFFFFFu;
#pragma unroll
      for (int nf = 0; nf < 4; nf++) {
        int col = n0 + wc + nf * 16 + l15;
        float d = c2[col] - 2.0f * acc[mf][nf][r];
        unsigned kk = packkey(d, col);
        if (kk < k1) { k2 = k1; k1 = kk; }
        else if (kk < k2) { k2 = kk; }
      }
      // 16-lane (same l4 = same row) top-2 butterfly over the wave's 64 cols
#pragma unroll
      for (int o = 1; o <= 8; o <<= 1) {
        unsigned b1 = (unsigned)__shfl_xor((int)k1, o);
        unsigned b2 = (unsigned)__shfl_xor((int)k2, o);
        unsigned m1 = umn(k1, b1);
        unsigned m2 = umn(umx(k1, b1), umn(k2, b2));
        k1 = m1; k2 = m2;
      }
      if (l15 == 0) {
        hk[wrow * 8 + (wv & 3) * 2 + 0] = k1;
        hk[wrow * 8 + (wv & 3) * 2 + 1] = k2;
      }
    }
  __syncthreads();
  if (t < 128) {
    unsigned q1[4], q2[4];
#pragma unroll
    for (int i = 0; i < 4; i++) {
      q1[i] = hk[t * 8 + i * 2];
      q2[i] = hk[t * 8 + i * 2 + 1];
    }
    unsigned a1 = umn(q1[0], q1[1]);
    unsigned a2 = umn(umx(q1[0], q1[1]), umn(q2[0], q2[1]));
    unsigned b1 = umn(q1[2], q1[3]);
    unsigned b2 = umn(umx(q1[2], q1[3]), umn(q2[2], q2[3]));
    unsigned m1 = umn(a1, b1);
    unsigned m2 = umn(umx(a1, b1), umn(a2, b2));
    size_t base = (size_t)(m0 + t) * 32 + ny * 2;
    pk[base + 0] = m1;
    pk[base + 1] = m2;
  }
}

// ---------------- candidate select + exact fp32 rescore + gather -----------
__global__ __launch_bounds__(256) void vq_out_kernel(
    const unsigned* __restrict__ pk, const float* __restrict__ x,
    const float* __restrict__ cb,
    float* __restrict__ outq, float* __restrict__ outidx) {
  int r = blockIdx.x * 4 + (threadIdx.x >> 6);
  int lane = threadIdx.x & 63;
  unsigned key = (lane < 32) ? pk[(size_t)r * 32 + lane] : 0xFFFFFFFFu;
  unsigned kmin = key;
#pragma unroll
  for (int o = 32; o >= 1; o >>= 1) kmin = umn(kmin, (unsigned)__shfl_xor((int)kmin, o));
  float dmin = unpackd(kmin);
  unsigned long long mask = __ballot(lane < 32 && unpackd(key) <= dmin + 2.0f);

  const float* xr = x + (size_t)r * C + lane * 8;
  float4 xa = *(const float4*)xr;
  float4 xb = *(const float4*)(xr + 4);

  float bestd = 3.4e38f;
  int   besti = 0x7fffffff;
  while (mask) {
    int l = __ffsll(mask) - 1;
    mask &= mask - 1;
    int col = ((unsigned)__shfl((int)key, l)) & 0xFFFu;
    const float* cr = cb + (size_t)col * C + lane * 8;
    float4 ca = *(const float4*)cr;
    float4 cb4 = *(const float4*)(cr + 4);
    float s = 0.f;
    s = fmaf(ca.x, ca.x - 2.f * xa.x, s);
    s = fmaf(ca.y, ca.y - 2.f * xa.y, s);
    s = fmaf(ca.z, ca.z - 2.f * xa.z, s);
    s = fmaf(ca.w, ca.w - 2.f * xa.w, s);
    s = fmaf(cb4.x, cb4.x - 2.f * xb.x, s);
    s = fmaf(cb4.y, cb4.y - 2.f * xb.y, s);
    s = fmaf(cb4.z, cb4.z - 2.f * xb.z, s);
    s = fmaf(cb4.w, cb4.w - 2.f * xb.w, s);
#pragma unroll
    for (int o = 32; o >= 1; o >>= 1) s += __shfl_xor(s, o);
    if (s < bestd || (s == bestd && col < besti)) { bestd = s; besti = col; }
  }
  const float4* src = (const float4*)(cb + (size_t)besti * C + lane * 8);
  float4*       dst = (float4*)(outq + (size_t)r * C + lane * 8);
  dst[0] = src[0];
  dst[1] = src[1];
  if (lane == 0) outidx[r] = (float)besti;
}

// ---------------- fused per-(window, head) attention (fp32) ----------------
// LDS: q, k, v only (48 KB -> 3 blocks/CU); pT aliases q (q fully consumed
// into qreg before softmax; extra barrier separates read/write).
__global__ __launch_bounds__(256) void attn_kernel(
    const float* __restrict__ qkv,   // chunk-local windowed rows x 1536
    const float* __restrict__ rpb,   // (225, 8)
    short* __restrict__ Hout, short* __restrict__ Lout,  // global windowed rows x 512
    int winOff, int shift) {
  int wl = blockIdx.x;
  int h  = blockIdx.y;
  int t  = threadIdx.x;
  __shared__ float q[64][64], k[64][64], v[64][64];   // 48 KiB
  float (*pT)[64] = q;   // reuse q's space for P^T

  const float* base = qkv + (size_t)wl * 64 * 1536 + h * 64;
#pragma unroll
  for (int rep = 0; rep < 4; rep++) {
    int f = t + rep * 256;
    int i = f >> 4, dq = (f & 15) * 4;
    const float* rowp = base + (size_t)i * 1536 + dq;
    float4 qv = *(const float4*)(rowp);
    float4 kv = *(const float4*)(rowp + 512);
    float4 vv = *(const float4*)(rowp + 1024);
    q[i][dq] = qv.x * 0.125f; q[i][dq + 1] = qv.y * 0.125f;
    q[i][dq + 2] = qv.z * 0.125f; q[i][dq + 3] = qv.w * 0.125f;
    *(float4*)&k[i][dq] = kv;
    *(float4*)&v[i][dq] = vv;
  }
  __syncthreads();

  int i  = t >> 2;
  int jg = t & 3;
  int wim = (winOff + wl) & 15;
  int wy = wim >> 2, wx = wim & 3;
  int iy = i >> 3, ix = i & 7;

  float qreg[64];
#pragma unroll
  for (int d = 0; d < 64; d += 4) *(float4*)&qreg[d] = *(float4*)&q[i][d];
  __syncthreads();   // all q reads done before pT (aliasing q) is written

  int ci = 0;
  if (shift) ci = region(wy * 8 + iy) * 3 + region(wx * 8 + ix);

  float sc[16];
#pragma unroll
  for (int jj = 0; jj < 16; jj++) {
    int j = jg * 16 + jj;
    float s = 0.f;
#pragma unroll
    for (int d = 0; d < 64; d += 4) {
      float4 kv = *(float4*)&k[j][d];
      s = fmaf(qreg[d], kv.x, s);
      s = fmaf(qreg[d + 1], kv.y, s);
      s = fmaf(qreg[d + 2], kv.z, s);
      s = fmaf(qreg[d + 3], kv.w, s);
    }
    int jy = j >> 3, jx = j & 7;
    s += rpb[((iy - jy + 7) * 15 + (ix - jx + 7)) * 8 + h];
    if (shift) {
      int cj = region(wy * 8 + jy) * 3 + region(wx * 8 + jx);
      if (ci != cj) s -= 100.0f;
    }
    sc[jj] = s;
  }
  float mx = sc[0];
#pragma unroll
  for (int jj = 1; jj < 16; jj++) mx = fmaxf(mx, sc[jj]);
  mx = fmaxf(mx, __shfl_xor(mx, 1));
  mx = fmaxf(mx, __shfl_xor(mx, 2));
  float sum = 0.f;
#pragma unroll
  for (int jj = 0; jj < 16; jj++) { sc[jj] = expf(sc[jj] - mx); sum += sc[jj]; }
  sum += __shfl_xor(sum, 1);
  sum += __shfl_xor(sum, 2);
  float inv = 1.0f / sum;
#pragma unroll
  for (int jj = 0; jj < 16; jj++) pT[jg * 16 + jj][i] = sc[jj] * inv;
  __syncthreads();

  float accv[16];
#pragma unroll
  for (int dd = 0; dd < 16; dd++) accv[dd] = 0.f;
  for (int j = 0; j < 64; j++) {
    float pij = pT[j][i];
#pragma unroll
    for (int dd = 0; dd < 16; dd += 4) {
      float4 vv = *(float4*)&v[j][jg * 16 + dd];
      accv[dd]     = fmaf(pij, vv.x, accv[dd]);
      accv[dd + 1] = fmaf(pij, vv.y, accv[dd + 1]);
      accv[dd + 2] = fmaf(pij, vv.z, accv[dd + 2]);
      accv[dd + 3] = fmaf(pij, vv.w, accv[dd + 3]);
    }
  }
  size_t obase = ((size_t)(winOff + wl) * 64 + i) * 512 + h * 64 + jg * 16;
  short8 hv, lv;
#pragma unroll
  for (int half = 0; half < 2; half++) {
#pragma unroll
    for (int j = 0; j < 8; j++) {
      short hh, ll;
      f2hsplit(accv[half * 8 + j], hh, ll);
      hv[j] = hh; lv[j] = ll;
    }
    *(short8*)&Hout[obase + half * 8] = hv;
    *(short8*)&Lout[obase + half * 8] = lv;
  }
}

}  // namespace

extern "C" void kernel_launch(void* const* d_in, const int* in_sizes, int n_in,
                              void* d_out, int out_size, void* d_ws, size_t ws_size,
                              hipStream_t stream) {
  const float* x_in = (const float*)d_in[0];
  const float* n1g  = (const float*)d_in[1];
  const float* n1b  = (const float*)d_in[2];
  const float* qkvw = (const float*)d_in[3];
  const float* qkvb = (const float*)d_in[4];
  const float* rpb  = (const float*)d_in[5];
  const float* pw   = (const float*)d_in[6];
  const float* pb   = (const float*)d_in[7];
  const float* n2g  = (const float*)d_in[8];
  const float* n2b  = (const float*)d_in[9];
  const float* f1w  = (const float*)d_in[10];
  const float* f1b  = (const float*)d_in[11];
  const float* f2w  = (const float*)d_in[12];
  const float* f2b_ = (const float*)d_in[13];
  const float* cb   = (const float*)d_in[14];

  float* outq   = (float*)d_out;
  float* outidx = outq + 16777216;
  short* Hbuf = (short*)d_out;                 // hi plane: first 32MB of outq
  short* Lbuf = Hbuf + (size_t)ROWS * 512;     // lo plane: second 32MB

  char* ws = (char*)d_ws;
  float* Abuf = (float*)ws;                               // 64MiB residual stream
  short* Wb   = (short*)(ws + ((size_t)64 << 20));        // 32MiB weight planes
  char*  Cbuf = ws + ((size_t)96 << 20);                  // chunk scratch
  const int Rrows = (ws_size >= ((size_t)232 << 20)) ? 16384
                  : (ws_size >= ((size_t)160 << 20)) ? 8192
                  : (ws_size >= ((size_t)128 << 20)) ? 4096 : 2048;

  const int SZ_QKV = 512 * 1536, SZ_P = 512 * 512, SZ_F1 = 512 * 2048, SZ_F2 = 2048 * 512;
  const int PB = (SZ_QKV + SZ_P + SZ_F1 + SZ_F2) * 2;
  short* cbH = Wb + (size_t)2 * PB;
  short* cbL = cbH + 4096 * 512;

  // ---- one-time (per launch) weight transpose + split ----
  for (int blk = 0; blk < 2; blk++) {
    short* base = Wb + (size_t)blk * PB;
    short* qH = base;          short* qL = qH + SZ_QKV;
    short* pH = qL + SZ_QKV;   short* pL = pH + SZ_P;
    short* f1H = pL + SZ_P;    short* f1L = f1H + SZ_F1;
    short* f2H = f1L + SZ_F1;  short* f2L = f2H + SZ_F2;
    wconvT_kernel<<<dim3(48, 16), dim3(32, 8), 0, stream>>>(qkvw + (size_t)blk * SZ_QKV, qH, qL, 512, 1536);
    wconvT_kernel<<<dim3(16, 16), dim3(32, 8), 0, stream>>>(pw + (size_t)blk * SZ_P, pH, pL, 512, 512);
    wconvT_kernel<<<dim3(64, 16), dim3(32, 8), 0, stream>>>(f1w + (size_t)blk * SZ_F1, f1H, f1L, 512, 2048);
    wconvT_kernel<<<dim3(16, 64), dim3(32, 8), 0, stream>>>(f2w + (size_t)blk * SZ_F2, f2H, f2L, 2048, 512);
  }
  wconv_kernel<<<2048, 256, 0, stream>>>(cb, cbH, cbL);

  const int nch = ROWS / Rrows;
  for (int blk = 0; blk < 2; blk++) {
    short* base = Wb + (size_t)blk * PB;
    short* qH = base;          short* qL = qH + SZ_QKV;
    short* pH = qL + SZ_QKV;   short* pL = pH + SZ_P;
    short* f1H = pL + SZ_P;    short* f1L = f1H + SZ_F1;
    short* f2H = f1L + SZ_F1;  short* f2L = f2H + SZ_F2;
    const float* xcur = blk ? (const float*)Abuf : x_in;
    int shift = blk ? 4 : 0;

    // LN1 + shift + window partition -> hi/lo planes (windowed order)
    ln_split_kernel<<<8192, 256, 0, stream>>>(xcur, Hbuf, Lbuf, n1g + blk * 512, n1b + blk * 512, shift, 1);

    // qkv GEMM (fp32 out) + attention (writes planes back in place)
    float* Cq = (float*)Cbuf;
    for (int ch = 0; ch < nch; ch++) {
      int r0 = ch * Rrows;
      mgemm<0><<<dim3(Rrows / 128, 12), 512, 0, stream>>>(
          Hbuf + (size_t)r0 * 512, Lbuf + (size_t)r0 * 512, qH, qL, 512,
          qkvb + blk * 1536, Cq, nullptr, nullptr, 1536,
          nullptr, 0, 0, 0);
      attn_kernel<<<dim3(Rrows / 64, 8), 256, 0, stream>>>(
          Cq, rpb + blk * 1800, Hbuf, Lbuf, r0 >> 6, shift);
    }

    // proj + window reverse + unshift + residual -> Abuf (fp32)
    mgemm<2><<<dim3(256, 4), 512, 0, stream>>>(
        Hbuf, Lbuf, pH, pL, 512, pb + blk * 512,
        Abuf, nullptr, nullptr, 512,
        blk ? (const float*)Abuf : x_in, 0, 1, shift);

    // LN2 -> planes (identity order)
    ln_split_kernel<<<8192, 256, 0, stream>>>(Abuf, Hbuf, Lbuf, n2g + blk * 512, n2b + blk * 512, 0, 0);

    // MLP; blk==1 fc2 also emits h/l planes (fused split for VQ)
    short* gh = (short*)Cbuf;
    short* gl = gh + (size_t)Rrows * 2048;
    for (int ch = 0; ch < nch; ch++) {
      int r0 = ch * Rrows;
      mgemm<1><<<dim3(Rrows / 128, 16), 512, 0, stream>>>(
          Hbuf + (size_t)r0 * 512, Lbuf + (size_t)r0 * 512, f1H, f1L, 512,
          f1b + blk * 2048, nullptr, gh, gl, 2048,
          nullptr, 0, 0, 0);
      if (blk == 0) {
        mgemm<2><<<dim3(Rrows / 128, 4), 512, 0, stream>>>(
            gh, gl, f2H, f2L, 2048, f2b_ + blk * 512,
            Abuf, nullptr, nullptr, 512,
            Abuf, r0, 0, 0);
      } else {
        mgemm<4><<<dim3(Rrows / 128, 4), 512, 0, stream>>>(
            gh, gl, f2H, f2L, 2048, f2b_ + blk * 512,
            Abuf, Hbuf, Lbuf, 512,
            Abuf, r0, 0, 0);
      }
    }
  }

  // ---- VQ: approx top-2/tile via single-pass fp16 GEMM, exact rescore ----
  float*    c2  = (float*)Cbuf;                              // 16 KB
  unsigned* pkb = (unsigned*)(Cbuf + ((size_t)64 << 10));    // 4 MiB: 32768 x 32 keys
  rowss_kernel<<<1024, 256, 0, stream>>>(cb, c2, 4096);
  vqgemm<<<4096, 512, 0, stream>>>(Hbuf, cbH, c2, pkb);
  vq_out_kernel<<<8192, 256, 0, stream>>>(pkb, Abuf, cb, outq, outidx);
}

// Round 13
// 2236.991 us; speedup vs baseline: 1.2176x; 1.0238x over previous
//
#include <hip/hip_runtime.h>
#include <math.h>

#define DEV __device__ __forceinline__

typedef __attribute__((ext_vector_type(8))) _Float16 f16x8;
typedef __attribute__((ext_vector_type(8))) short short8;
typedef __attribute__((ext_vector_type(4))) float f32x4;

namespace {

constexpr int C = 512;
constexpr int ROWS = 32768;   // B * L
constexpr float LSCALE = 2048.0f;        // lo-plane pre-scale (2^11)
constexpr float LINV   = 1.0f / 2048.0f;
constexpr float F16MIN = 6.1035156e-5f;  // fp16 min normal

// fp32 -> fp16 hi/lo split. h = RTN(x) (flushed to 0 below normal range),
// l = RTN((x - h) * 2^11). Ensures all MFMA inputs are 0 or normal fp16.
DEV void f2hsplit(float x, short& hs, short& ls) {
  _Float16 h = (_Float16)x;
  float hf = (float)h;
  if (fabsf(hf) < F16MIN) { h = (_Float16)0.0f; hf = 0.f; }
  _Float16 l = (_Float16)((x - hf) * LSCALE);
  if (fabsf((float)l) < F16MIN) l = (_Float16)0.0f;
  hs = __builtin_bit_cast(short, h);
  ls = __builtin_bit_cast(short, l);
}

DEV unsigned umn(unsigned a, unsigned b) { return a < b ? a : b; }
DEV unsigned umx(unsigned a, unsigned b) { return a > b ? a : b; }

// monotone key: high 20 bits = sign-flipped fp32 distance, low 12 = col idx.
DEV unsigned packkey(float d, int col) {
  unsigned u = __builtin_bit_cast(unsigned, d);
  u = (u & 0x80000000u) ? ~u : (u | 0x80000000u);
  return (u & 0xFFFFF000u) | (unsigned)col;
}
DEV float unpackd(unsigned k) {
  unsigned u = (k & 0x80000000u) ? (k ^ 0x80000000u) : ~k;
  return __builtin_bit_cast(float, u);
}

// windowed row r -> flat row in (b, y, x) order, for roll by `shift`.
DEV int rowmap(int r, int shift) {
  int b  = r >> 10;
  int w  = (r >> 6) & 15;
  int wy = w >> 2, wx = w & 3;
  int ii = r & 63;
  int iy = ii >> 3, ix = ii & 7;
  int y = (wy * 8 + iy + shift) & 31;
  int x = (wx * 8 + ix + shift) & 31;
  return (b << 10) + (y << 5) + x;
}

DEV int region(int y) { return (y < 24) ? 0 : ((y < 28) ? 1 : 2); }

typedef __attribute__((address_space(1))) const unsigned int gu32;
typedef __attribute__((address_space(3))) unsigned int lu32;
DEV void gload16(const void* g, void* l) {
  __builtin_amdgcn_global_load_lds((gu32*)g, (lu32*)l, 16, 0, 0);
}

// XCD-local hierarchical tile map: each XCD owns a contiguous m-slab;
// within it, groups of GM m-tiles sweep all n-tiles (A-group stays L2-hot).
DEV void tilemap(int Mt, int Nt, int GM, int& mt, int& nt) {
  int bid = blockIdx.y * Mt + blockIdx.x;
  if ((Mt & 7) == 0) {
    int xcd = bid & 7, idx = bid >> 3;
    int Mt8 = Mt >> 3;
    if (GM > Mt8) GM = Mt8;
    int span = GM * Nt;
    int g = idx / span, rem = idx % span;
    nt = rem / GM;
    mt = xcd * Mt8 + g * GM + rem % GM;
  } else {
    mt = blockIdx.x; nt = blockIdx.y;
  }
}

// ---------------- LayerNorm -> fp16 hi/lo planes ---------------------------
__global__ __launch_bounds__(256) void ln_split_kernel(
    const float* __restrict__ src, short* __restrict__ Hp, short* __restrict__ Lp,
    const float* __restrict__ g, const float* __restrict__ b,
    int shift, int windowed) {
  int wid  = (blockIdx.x * 256 + threadIdx.x) >> 6;
  int lane = threadIdx.x & 63;
  if (wid >= ROWS) return;
  int srcRow = windowed ? rowmap(wid, shift) : wid;
  const float* s = src + (size_t)srcRow * C + lane * 8;
  float v[8];
  *(float4*)(v)     = *(const float4*)(s);
  *(float4*)(v + 4) = *(const float4*)(s + 4);
  float sum = 0.f;
#pragma unroll
  for (int j = 0; j < 8; j++) sum += v[j];
#pragma unroll
  for (int o = 32; o >= 1; o >>= 1) sum += __shfl_xor(sum, o);
  float mu = sum * (1.0f / 512.0f);
  float vs = 0.f;
#pragma unroll
  for (int j = 0; j < 8; j++) { float d = v[j] - mu; vs += d * d; }
#pragma unroll
  for (int o = 32; o >= 1; o >>= 1) vs += __shfl_xor(vs, o);
  float rs = rsqrtf(vs * (1.0f / 512.0f) + 1e-5f);
  float gg[8], bb[8];
  *(float4*)gg       = *(const float4*)&g[lane * 8];
  *(float4*)(gg + 4) = *(const float4*)&g[lane * 8 + 4];
  *(float4*)bb       = *(const float4*)&b[lane * 8];
  *(float4*)(bb + 4) = *(const float4*)&b[lane * 8 + 4];
  short8 hv, lv;
#pragma unroll
  for (int j = 0; j < 8; j++) {
    float o8 = (v[j] - mu) * rs * gg[j] + bb[j];
    short hh, ll;
    f2hsplit(o8, hh, ll);
    hv[j] = hh; lv[j] = ll;
  }
  *(short8*)&Hp[(size_t)wid * C + lane * 8] = hv;
  *(short8*)&Lp[(size_t)wid * C + lane * 8] = lv;
}

// ---------------- row sum of squares (codebook) ----------------------------
__global__ __launch_bounds__(256) void rowss_kernel(
    const float* __restrict__ src, float* __restrict__ dst, int nrows) {
  int wid  = (blockIdx.x * 256 + threadIdx.x) >> 6;
  int lane = threadIdx.x & 63;
  if (wid >= nrows) return;
  const float* s = src + (size_t)wid * C + lane * 8;
  float4 a  = *(const float4*)s;
  float4 b4 = *(const float4*)(s + 4);
  float sum = a.x*a.x + a.y*a.y + a.z*a.z + a.w*a.w
            + b4.x*b4.x + b4.y*b4.y + b4.z*b4.z + b4.w*b4.w;
#pragma unroll
  for (int o = 32; o >= 1; o >>= 1) sum += __shfl_xor(sum, o);
  if (lane == 0) dst[wid] = sum;
}

// ---------------- weight transpose + split: W(K,N) -> H/L (N,K) ------------
__global__ __launch_bounds__(256) void wconvT_kernel(
    const float* __restrict__ W, short* __restrict__ Hp, short* __restrict__ Lp,
    int K, int N) {
  __shared__ float t[32][33];
  int tx = threadIdx.x, ty = threadIdx.y;
  int n0 = blockIdx.x * 32, k0 = blockIdx.y * 32;
#pragma unroll
  for (int r = 0; r < 4; r++) {
    int k = ty + r * 8;
    t[k][tx] = W[(size_t)(k0 + k) * N + n0 + tx];
  }
  __syncthreads();
#pragma unroll
  for (int r = 0; r < 4; r++) {
    int n = ty + r * 8;
    short h, l;
    f2hsplit(t[tx][n], h, l);
    Hp[(size_t)(n0 + n) * K + k0 + tx] = h;
    Lp[(size_t)(n0 + n) * K + k0 + tx] = l;
  }
}

// ---------------- codebook split (already N-major) -------------------------
__global__ __launch_bounds__(256) void wconv_kernel(
    const float* __restrict__ W, short* __restrict__ Hp, short* __restrict__ Lp) {
  size_t i = ((size_t)blockIdx.x * 256 + threadIdx.x) * 4;
  float4 a = *(const float4*)&W[i];
  float v[4] = {a.x, a.y, a.z, a.w};
  short hv[4], lv[4];
#pragma unroll
  for (int j = 0; j < 4; j++) f2hsplit(v[j], hv[j], lv[j]);
  *(short4*)&Hp[i] = *(short4*)hv;
  *(short4*)&Lp[i] = *(short4*)lv;
}

// -- fp16-pair MFMA GEMM, 128x128 tile, BK=32, 8 waves, LDS double-buffer ---
// A planes [M][K], B planes [N][K]; C = A * B^T (+ epilogue).
// acc = accH(h*h) + 2^-11 * accL(h*lw + la*h); la/lw are pre-scaled by 2^11.
// EPI: 0 = fp32 out+bias (qkv); 1 = gelu -> hi/lo planes (fc1);
//      2 = +bias+resid fp32 (proj/fc2); 4 = EPI2 + h/l plane store
template <int EPI>
__global__ __launch_bounds__(512) void mgemm(
    const short* __restrict__ Ah, const short* __restrict__ Al,
    const short* __restrict__ Bh, const short* __restrict__ Bl,
    const int K, const float* __restrict__ bias,
    float* __restrict__ outF, short* __restrict__ outH, short* __restrict__ outL,
    const int ldo,
    const float* __restrict__ resid, const int rowOff, const int perm, const int shift) {
  __shared__ short lds[32768];   // 2 buffers x (Ah|Bh|Al|Bl) 128x32 fp16 tiles
  int mt, nt;
  tilemap(gridDim.x, gridDim.y, 4, mt, nt);   // GM=4: 1MB A-group (H+L)
  const int m0 = mt * 128, n0 = nt * 128;
  const int t  = threadIdx.x;
  const int wv = t >> 6, ln = t & 63;
  const int wr = (wv >> 2) * 64, wc = (wv & 3) * 32;   // wave tile 64x32
  const int l15 = ln & 15, l4 = ln >> 4;

  f32x4 accH[4][2], accL[4][2];
#pragma unroll
  for (int mf = 0; mf < 4; mf++)
#pragma unroll
    for (int nf = 0; nf < 2; nf++) {
      accH[mf][nf] = (f32x4){0.f, 0.f, 0.f, 0.f};
      accL[mf][nf] = (f32x4){0.f, 0.f, 0.f, 0.f};
    }

  const int srow = ln >> 2;
  const int scol = ((ln & 3) ^ ((ln >> 3) & 3)) * 8;

  auto stage = [&](int buf, int k0) {
    short* b = lds + buf * 16384;
    size_t ra = (size_t)(m0 + wv * 16 + srow) * K + k0 + scol;
    size_t rb = (size_t)(n0 + wv * 16 + srow) * K + k0 + scol;
    gload16(Ah + ra, b + wv * 512);
    gload16(Bh + rb, b + 4096 + wv * 512);
    gload16(Al + ra, b + 8192 + wv * 512);
    gload16(Bl + rb, b + 12288 + wv * 512);
  };
  auto frag = [&](const short* lt, int rbase) -> f16x8 {
    int r = rbase + l15;
    int kc = l4 ^ ((r >> 1) & 3);
    return *(const f16x8*)(lt + (r >> 4) * 512 + (r & 15) * 32 + kc * 8);
  };

  stage(0, 0);
  __syncthreads();
  int cur = 0;
  for (int k0 = 0; k0 < K; k0 += 32) {
    if (k0 + 32 < K) stage(cur ^ 1, k0 + 32);
    const short* base = lds + cur * 16384;
    f16x8 ah[4], bh[2], bl[2];
#pragma unroll
    for (int mf = 0; mf < 4; mf++) ah[mf] = frag(base, wr + mf * 16);
#pragma unroll
    for (int nf = 0; nf < 2; nf++) bh[nf] = frag(base + 4096, wc + nf * 16);
    __builtin_amdgcn_s_setprio(1);
#pragma unroll
    for (int mf = 0; mf < 4; mf++)
#pragma unroll
      for (int nf = 0; nf < 2; nf++)
        accH[mf][nf] = __builtin_amdgcn_mfma_f32_16x16x32_f16(ah[mf], bh[nf], accH[mf][nf], 0, 0, 0);
    __builtin_amdgcn_s_setprio(0);
#pragma unroll
    for (int nf = 0; nf < 2; nf++) bl[nf] = frag(base + 12288, wc + nf * 16);
    __builtin_amdgcn_s_setprio(1);
#pragma unroll
    for (int mf = 0; mf < 4; mf++)
#pragma unroll
      for (int nf = 0; nf < 2; nf++)
        accL[mf][nf] = __builtin_amdgcn_mfma_f32_16x16x32_f16(ah[mf], bl[nf], accL[mf][nf], 0, 0, 0);
#pragma unroll
    for (int mf = 0; mf < 4; mf++) {
      f16x8 al = frag(base + 8192, wr + mf * 16);
#pragma unroll
      for (int nf = 0; nf < 2; nf++)
        accL[mf][nf] = __builtin_amdgcn_mfma_f32_16x16x32_f16(al, bh[nf], accL[mf][nf], 0, 0, 0);
    }
    __builtin_amdgcn_s_setprio(0);
    __syncthreads();
    cur ^= 1;
  }

  f32x4 acc[4][2];
#pragma unroll
  for (int mf = 0; mf < 4; mf++)
#pragma unroll
    for (int nf = 0; nf < 2; nf++)
#pragma unroll
      for (int r = 0; r < 4; r++)
        acc[mf][nf][r] = fmaf(accL[mf][nf][r], LINV, accH[mf][nf][r]);

  if (EPI == 0) {
#pragma unroll
    for (int mf = 0; mf < 4; mf++)
#pragma unroll
      for (int r = 0; r < 4; r++) {
        int row = m0 + wr + mf * 16 + l4 * 4 + r;
        float* op = outF + (size_t)row * ldo;
#pragma unroll
        for (int nf = 0; nf < 2; nf++) {
          int col = n0 + wc + nf * 16 + l15;
          op[col] = acc[mf][nf][r] + bias[col];
        }
      }
  } else if (EPI == 1) {
#pragma unroll
    for (int mf = 0; mf < 4; mf++)
#pragma unroll
      for (int r = 0; r < 4; r++) {
        int row = m0 + wr + mf * 16 + l4 * 4 + r;
#pragma unroll
        for (int nf = 0; nf < 2; nf++) {
          int col = n0 + wc + nf * 16 + l15;
          float v = acc[mf][nf][r] + bias[col];
          v = 0.5f * v * (1.0f + erff(v * 0.70710678118654752f));
          short h, l;
          f2hsplit(v, h, l);
          outH[(size_t)row * ldo + col] = h;
          outL[(size_t)row * ldo + col] = l;
        }
      }
  } else {  // EPI == 2 or 4
#pragma unroll
    for (int mf = 0; mf < 4; mf++)
#pragma unroll
      for (int r = 0; r < 4; r++) {
        int row = m0 + wr + mf * 16 + l4 * 4 + r;
        int orow = perm ? rowmap(row, shift) : (row + rowOff);
        const float* rp = resid + (size_t)orow * ldo;
        float* op = outF + (size_t)orow * ldo;
#pragma unroll
        for (int nf = 0; nf < 2; nf++) {
          int col = n0 + wc + nf * 16 + l15;
          float v = rp[col] + acc[mf][nf][r] + bias[col];
          op[col] = v;
          if (EPI == 4) {
            short h, l;
            f2hsplit(v, h, l);
            outH[(size_t)orow * ldo + col] = h;
            outL[(size_t)orow * ldo + col] = l;
          }
        }
      }
  }
}

// -- VQ distance GEMM: h*h only, block 128x256, 8 waves of 64x64, BK=32 -----
// 4x4 fragment reuse. Single-buffer, 2 barriers. XCD-grouped tile order
// (GM=8 -> 1MB A-group L2-resident across the 16-n sweep).
// top-2 per 256-col tile emitted as packed keys; exact rescore downstream.
__global__ __launch_bounds__(512) void vqgemm(
    const short* __restrict__ Ah, const short* __restrict__ Bh,
    const float* __restrict__ c2, unsigned* __restrict__ pk) {
  __shared__ short lds[12288];   // A 128x32 (8 chunks) | B 256x32 (16 chunks)
  const int bid = blockIdx.x;
  const int xcd = bid & 7, idx = bid >> 3;
  const int g  = idx >> 7;             // 0..3 (group of 8 m-tiles)
  const int ny = (idx >> 3) & 15;      // 0..15
  const int mi = idx & 7;              // 0..7
  const int m0 = (xcd * 32 + g * 8 + mi) * 128;
  const int n0 = ny * 256;
  const int K = 512;
  const int t  = threadIdx.x;
  const int wv = t >> 6, ln = t & 63;
  const int wr = (wv >> 2) * 64, wc = (wv & 3) * 64;  // wave tile 64x64
  const int l15 = ln & 15, l4 = ln >> 4;

  f32x4 acc[4][4];
#pragma unroll
  for (int mf = 0; mf < 4; mf++)
#pragma unroll
    for (int nf = 0; nf < 4; nf++) acc[mf][nf] = (f32x4){0.f, 0.f, 0.f, 0.f};

  const int srow = ln >> 2;
  const int scol = ((ln & 3) ^ ((ln >> 3) & 3)) * 8;

  short* As = lds;            // 8 chunks
  short* Bs = lds + 4096;     // 16 chunks

  auto frag = [&](const short* lt, int rbase) -> f16x8 {
    int r = rbase + l15;
    int kc = l4 ^ ((r >> 1) & 3);
    return *(const f16x8*)(lt + (r >> 4) * 512 + (r & 15) * 32 + kc * 8);
  };

  for (int k0 = 0; k0 < K; k0 += 32) {
#pragma unroll
    for (int q = 0; q < 3; q++) {
      int s = wv * 3 + q;                 // 0..23: 8 A chunks then 16 B chunks
      int isA = (s < 8);
      int c = isA ? s : (s - 8);
      const short* src = isA ? Ah : Bh;
      short* dst = (isA ? As : Bs) + c * 512;
      int rowbase = (isA ? m0 : n0) + c * 16;
      size_t ga = (size_t)(rowbase + srow) * K + k0 + scol;
      gload16(src + ga, dst);
    }
    __syncthreads();
    f16x8 ah[4], bh[4];
#pragma unroll
    for (int mf = 0; mf < 4; mf++) ah[mf] = frag(As, wr + mf * 16);
#pragma unroll
    for (int nf = 0; nf < 4; nf++) bh[nf] = frag(Bs, wc + nf * 16);
    __builtin_amdgcn_s_setprio(1);
#pragma unroll
    for (int mf = 0; mf < 4; mf++)
#pragma unroll
      for (int nf = 0; nf < 4; nf++)
        acc[mf][nf] = __builtin_amdgcn_mfma_f32_16x16x32_f16(ah[mf], bh[nf], acc[mf][nf], 0, 0, 0);
    __builtin_amdgcn_s_setprio(0);
    __syncthreads();
  }

  // top-2 per row over this 256-col tile
  unsigned* hk = (unsigned*)(void*)lds;   // [128 rows][4 nwaves][2] = 4 KB
#pragma unroll
  for (int mf = 0; mf < 4; mf++)
#pragma unroll
    for (int r = 0; r < 4; r++) {
      int wrow = wr + mf * 16 + l4 * 4 + r;
      unsigned k1 = 0xFFFFFFFFu, k2 = 0xFFFFFFFFu;
#pragma unroll
      for (int nf = 0; nf < 4; nf++) {
        int col = n0 + wc + nf * 16 + l15;
        float d = c2[col] - 2.0f * acc[mf][nf][r];
        unsigned kk = packkey(d, col);
        if (kk < k1) { k2 = k1; k1 = kk; }
        else if (kk < k2) { k2 = kk; }
      }
      // 16-lane (same l4 = same row) top-2 butterfly over the wave's 64 cols
#pragma unroll
      for (int o = 1; o <= 8; o <<= 1) {
        unsigned b1 = (unsigned)__shfl_xor((int)k1, o);
        unsigned b2 = (unsigned)__shfl_xor((int)k2, o);
        unsigned m1 = umn(k1, b1);
        unsigned m2 = umn(umx(k1, b1), umn(k2, b2));
        k1 = m1; k2 = m2;
      }
      if (l15 == 0) {
        hk[wrow * 8 + (wv & 3) * 2 + 0] = k1;
        hk[wrow * 8 + (wv & 3) * 2 + 1] = k2;
      }
    }
  __syncthreads();
  if (t < 128) {
    unsigned q1[4], q2[4];
#pragma unroll
    for (int i = 0; i < 4; i++) {
      q1[i] = hk[t * 8 + i * 2];
      q2[i] = hk[t * 8 + i * 2 + 1];
    }
    unsigned a1 = umn(q1[0], q1[1]);
    unsigned a2 = umn(umx(q1[0], q1[1]), umn(q2[0], q2[1]));
    unsigned b1 = umn(q1[2], q1[3]);
    unsigned b2 = umn(umx(q1[2], q1[3]), umn(q2[2], q2[3]));
    unsigned m1 = umn(a1, b1);
    unsigned m2 = umn(umx(a1, b1), umn(a2, b2));
    size_t base = (size_t)(m0 + t) * 32 + ny * 2;
    pk[base + 0] = m1;
    pk[base + 1] = m2;
  }
}

// ---------------- candidate select + exact fp32 rescore + gather -----------
__global__ __launch_bounds__(256) void vq_out_kernel(
    const unsigned* __restrict__ pk, const float* __restrict__ x,
    const float* __restrict__ cb,
    float* __restrict__ outq, float* __restrict__ outidx) {
  int r = blockIdx.x * 4 + (threadIdx.x >> 6);
  int lane = threadIdx.x & 63;
  unsigned key = (lane < 32) ? pk[(size_t)r * 32 + lane] : 0xFFFFFFFFu;
  unsigned kmin = key;
#pragma unroll
  for (int o = 32; o >= 1; o >>= 1) kmin = umn(kmin, (unsigned)__shfl_xor((int)kmin, o));
  float dmin = unpackd(kmin);
  unsigned long long mask = __ballot(lane < 32 && unpackd(key) <= dmin + 2.0f);

  const float* xr = x + (size_t)r * C + lane * 8;
  float4 xa = *(const float4*)xr;
  float4 xb = *(const float4*)(xr + 4);

  float bestd = 3.4e38f;
  int   besti = 0x7fffffff;
  while (mask) {
    int l = __ffsll(mask) - 1;
    mask &= mask - 1;
    int col = ((unsigned)__shfl((int)key, l)) & 0xFFFu;
    const float* cr = cb + (size_t)col * C + lane * 8;
    float4 ca = *(const float4*)cr;
    float4 cb4 = *(const float4*)(cr + 4);
    float s = 0.f;
    s = fmaf(ca.x, ca.x - 2.f * xa.x, s);
    s = fmaf(ca.y, ca.y - 2.f * xa.y, s);
    s = fmaf(ca.z, ca.z - 2.f * xa.z, s);
    s = fmaf(ca.w, ca.w - 2.f * xa.w, s);
    s = fmaf(cb4.x, cb4.x - 2.f * xb.x, s);
    s = fmaf(cb4.y, cb4.y - 2.f * xb.y, s);
    s = fmaf(cb4.z, cb4.z - 2.f * xb.z, s);
    s = fmaf(cb4.w, cb4.w - 2.f * xb.w, s);
#pragma unroll
    for (int o = 32; o >= 1; o >>= 1) s += __shfl_xor(s, o);
    if (s < bestd || (s == bestd && col < besti)) { bestd = s; besti = col; }
  }
  const float4* src = (const float4*)(cb + (size_t)besti * C + lane * 8);
  float4*       dst = (float4*)(outq + (size_t)r * C + lane * 8);
  dst[0] = src[0];
  dst[1] = src[1];
  if (lane == 0) outidx[r] = (float)besti;
}

// ---------------- fused per-(window, head) attention (fp32) ----------------
// LDS: q, k, v only (48 KB -> 3 blocks/CU); pT aliases q (q fully consumed
// into qreg before softmax; extra barrier separates read/write).
__global__ __launch_bounds__(256) void attn_kernel(
    const float* __restrict__ qkv,   // chunk-local windowed rows x 1536
    const float* __restrict__ rpb,   // (225, 8)
    short* __restrict__ Hout, short* __restrict__ Lout,  // global windowed rows x 512
    int winOff, int shift) {
  int wl = blockIdx.x;
  int h  = blockIdx.y;
  int t  = threadIdx.x;
  __shared__ float q[64][64], k[64][64], v[64][64];   // 48 KiB
  float (*pT)[64] = q;   // reuse q's space for P^T

  const float* base = qkv + (size_t)wl * 64 * 1536 + h * 64;
#pragma unroll
  for (int rep = 0; rep < 4; rep++) {
    int f = t + rep * 256;
    int i = f >> 4, dq = (f & 15) * 4;
    const float* rowp = base + (size_t)i * 1536 + dq;
    float4 qv = *(const float4*)(rowp);
    float4 kv = *(const float4*)(rowp + 512);
    float4 vv = *(const float4*)(rowp + 1024);
    q[i][dq] = qv.x * 0.125f; q[i][dq + 1] = qv.y * 0.125f;
    q[i][dq + 2] = qv.z * 0.125f; q[i][dq + 3] = qv.w * 0.125f;
    *(float4*)&k[i][dq] = kv;
    *(float4*)&v[i][dq] = vv;
  }
  __syncthreads();

  int i  = t >> 2;
  int jg = t & 3;
  int wim = (winOff + wl) & 15;
  int wy = wim >> 2, wx = wim & 3;
  int iy = i >> 3, ix = i & 7;

  float qreg[64];
#pragma unroll
  for (int d = 0; d < 64; d += 4) *(float4*)&qreg[d] = *(float4*)&q[i][d];
  __syncthreads();   // all q reads done before pT (aliasing q) is written

  int ci = 0;
  if (shift) ci = region(wy * 8 + iy) * 3 + region(wx * 8 + ix);

  float sc[16];
#pragma unroll
  for (int jj = 0; jj < 16; jj++) {
    int j = jg * 16 + jj;
    float s = 0.f;
#pragma unroll
    for (int d = 0; d < 64; d += 4) {
      float4 kv = *(float4*)&k[j][d];
      s = fmaf(qreg[d], kv.x, s);
      s = fmaf(qreg[d + 1], kv.y, s);
      s = fmaf(qreg[d + 2], kv.z, s);
      s = fmaf(qreg[d + 3], kv.w, s);
    }
    int jy = j >> 3, jx = j & 7;
    s += rpb[((iy - jy + 7) * 15 + (ix - jx + 7)) * 8 + h];
    if (shift) {
      int cj = region(wy * 8 + jy) * 3 + region(wx * 8 + jx);
      if (ci != cj) s -= 100.0f;
    }
    sc[jj] = s;
  }
  float mx = sc[0];
#pragma unroll
  for (int jj = 1; jj < 16; jj++) mx = fmaxf(mx, sc[jj]);
  mx = fmaxf(mx, __shfl_xor(mx, 1));
  mx = fmaxf(mx, __shfl_xor(mx, 2));
  float sum = 0.f;
#pragma unroll
  for (int jj = 0; jj < 16; jj++) { sc[jj] = expf(sc[jj] - mx); sum += sc[jj]; }
  sum += __shfl_xor(sum, 1);
  sum += __shfl_xor(sum, 2);
  float inv = 1.0f / sum;
#pragma unroll
  for (int jj = 0; jj < 16; jj++) pT[jg * 16 + jj][i] = sc[jj] * inv;
  __syncthreads();

  float accv[16];
#pragma unroll
  for (int dd = 0; dd < 16; dd++) accv[dd] = 0.f;
  for (int j = 0; j < 64; j++) {
    float pij = pT[j][i];
#pragma unroll
    for (int dd = 0; dd < 16; dd += 4) {
      float4 vv = *(float4*)&v[j][jg * 16 + dd];
      accv[dd]     = fmaf(pij, vv.x, accv[dd]);
      accv[dd + 1] = fmaf(pij, vv.y, accv[dd + 1]);
      accv[dd + 2] = fmaf(pij, vv.z, accv[dd + 2]);
      accv[dd + 3] = fmaf(pij, vv.w, accv[dd + 3]);
    }
  }
  size_t obase = ((size_t)(winOff + wl) * 64 + i) * 512 + h * 64 + jg * 16;
  short8 hv, lv;
#pragma unroll
  for (int half = 0; half < 2; half++) {
#pragma unroll
    for (int j = 0; j < 8; j++) {
      short hh, ll;
      f2hsplit(accv[half * 8 + j], hh, ll);
      hv[j] = hh; lv[j] = ll;
    }
    *(short8*)&Hout[obase + half * 8] = hv;
    *(short8*)&Lout[obase + half * 8] = lv;
  }
}

}  // namespace

extern "C" void kernel_launch(void* const* d_in, const int* in_sizes, int n_in,
                              void* d_out, int out_size, void* d_ws, size_t ws_size,
                              hipStream_t stream) {
  const float* x_in = (const float*)d_in[0];
  const float* n1g  = (const float*)d_in[1];
  const float* n1b  = (const float*)d_in[2];
  const float* qkvw = (const float*)d_in[3];
  const float* qkvb = (const float*)d_in[4];
  const float* rpb  = (const float*)d_in[5];
  const float* pw   = (const float*)d_in[6];
  const float* pb   = (const float*)d_in[7];
  const float* n2g  = (const float*)d_in[8];
  const float* n2b  = (const float*)d_in[9];
  const float* f1w  = (const float*)d_in[10];
  const float* f1b  = (const float*)d_in[11];
  const float* f2w  = (const float*)d_in[12];
  const float* f2b_ = (const float*)d_in[13];
  const float* cb   = (const float*)d_in[14];

  float* outq   = (float*)d_out;
  float* outidx = outq + 16777216;
  short* Hbuf = (short*)d_out;                 // hi plane: first 32MB of outq
  short* Lbuf = Hbuf + (size_t)ROWS * 512;     // lo plane: second 32MB

  char* ws = (char*)d_ws;
  float* Abuf = (float*)ws;                               // 64MiB residual stream
  short* Wb   = (short*)(ws + ((size_t)64 << 20));        // 32MiB weight planes
  char*  Cbuf = ws + ((size_t)96 << 20);                  // chunk scratch
  const int Rrows = (ws_size >= ((size_t)232 << 20)) ? 16384
                  : (ws_size >= ((size_t)160 << 20)) ? 8192
                  : (ws_size >= ((size_t)128 << 20)) ? 4096 : 2048;

  const int SZ_QKV = 512 * 1536, SZ_P = 512 * 512, SZ_F1 = 512 * 2048, SZ_F2 = 2048 * 512;
  const int PB = (SZ_QKV + SZ_P + SZ_F1 + SZ_F2) * 2;
  short* cbH = Wb + (size_t)2 * PB;
  short* cbL = cbH + 4096 * 512;

  // ---- one-time (per launch) weight transpose + split ----
  for (int blk = 0; blk < 2; blk++) {
    short* base = Wb + (size_t)blk * PB;
    short* qH = base;          short* qL = qH + SZ_QKV;
    short* pH = qL + SZ_QKV;   short* pL = pH + SZ_P;
    short* f1H = pL + SZ_P;    short* f1L = f1H + SZ_F1;
    short* f2H = f1L + SZ_F1;  short* f2L = f2H + SZ_F2;
    wconvT_kernel<<<dim3(48, 16), dim3(32, 8), 0, stream>>>(qkvw + (size_t)blk * SZ_QKV, qH, qL, 512, 1536);
    wconvT_kernel<<<dim3(16, 16), dim3(32, 8), 0, stream>>>(pw + (size_t)blk * SZ_P, pH, pL, 512, 512);
    wconvT_kernel<<<dim3(64, 16), dim3(32, 8), 0, stream>>>(f1w + (size_t)blk * SZ_F1, f1H, f1L, 512, 2048);
    wconvT_kernel<<<dim3(16, 64), dim3(32, 8), 0, stream>>>(f2w + (size_t)blk * SZ_F2, f2H, f2L, 2048, 512);
  }
  wconv_kernel<<<2048, 256, 0, stream>>>(cb, cbH, cbL);

  const int nch = ROWS / Rrows;
  for (int blk = 0; blk < 2; blk++) {
    short* base = Wb + (size_t)blk * PB;
    short* qH = base;          short* qL = qH + SZ_QKV;
    short* pH = qL + SZ_QKV;   short* pL = pH + SZ_P;
    short* f1H = pL + SZ_P;    short* f1L = f1H + SZ_F1;
    short* f2H = f1L + SZ_F1;  short* f2L = f2H + SZ_F2;
    const float* xcur = blk ? (const float*)Abuf : x_in;
    int shift = blk ? 4 : 0;

    // LN1 + shift + window partition -> hi/lo planes (windowed order)
    ln_split_kernel<<<8192, 256, 0, stream>>>(xcur, Hbuf, Lbuf, n1g + blk * 512, n1b + blk * 512, shift, 1);

    // qkv GEMM (fp32 out) + attention (writes planes back in place)
    float* Cq = (float*)Cbuf;
    for (int ch = 0; ch < nch; ch++) {
      int r0 = ch * Rrows;
      mgemm<0><<<dim3(Rrows / 128, 12), 512, 0, stream>>>(
          Hbuf + (size_t)r0 * 512, Lbuf + (size_t)r0 * 512, qH, qL, 512,
          qkvb + blk * 1536, Cq, nullptr, nullptr, 1536,
          nullptr, 0, 0, 0);
      attn_kernel<<<dim3(Rrows / 64, 8), 256, 0, stream>>>(
          Cq, rpb + blk * 1800, Hbuf, Lbuf, r0 >> 6, shift);
    }

    // proj + window reverse + unshift + residual -> Abuf (fp32)
    mgemm<2><<<dim3(256, 4), 512, 0, stream>>>(
        Hbuf, Lbuf, pH, pL, 512, pb + blk * 512,
        Abuf, nullptr, nullptr, 512,
        blk ? (const float*)Abuf : x_in, 0, 1, shift);

    // LN2 -> planes (identity order)
    ln_split_kernel<<<8192, 256, 0, stream>>>(Abuf, Hbuf, Lbuf, n2g + blk * 512, n2b + blk * 512, 0, 0);

    // MLP; blk==1 fc2 also emits h/l planes (fused split for VQ)
    short* gh = (short*)Cbuf;
    short* gl = gh + (size_t)Rrows * 2048;
    for (int ch = 0; ch < nch; ch++) {
      int r0 = ch * Rrows;
      mgemm<1><<<dim3(Rrows / 128, 16), 512, 0, stream>>>(
          Hbuf + (size_t)r0 * 512, Lbuf + (size_t)r0 * 512, f1H, f1L, 512,
          f1b + blk * 2048, nullptr, gh, gl, 2048,
          nullptr, 0, 0, 0);
      if (blk == 0) {
        mgemm<2><<<dim3(Rrows / 128, 4), 512, 0, stream>>>(
            gh, gl, f2H, f2L, 2048, f2b_ + blk * 512,
            Abuf, nullptr, nullptr, 512,
            Abuf, r0, 0, 0);
      } else {
        mgemm<4><<<dim3(Rrows / 128, 4), 512, 0, stream>>>(
            gh, gl, f2H, f2L, 2048, f2b_ + blk * 512,
            Abuf, Hbuf, Lbuf, 512,
            Abuf, r0, 0, 0);
      }
    }
  }

  // ---- VQ: approx top-2/tile via single-pass fp16 GEMM, exact rescore ----
  float*    c2  = (float*)Cbuf;                              // 16 KB
  unsigned* pkb = (unsigned*)(Cbuf + ((size_t)64 << 10));    // 4 MiB: 32768 x 32 keys
  rowss_kernel<<<1024, 256, 0, stream>>>(cb, c2, 4096);
  vqgemm<<<4096, 512, 0, stream>>>(Hbuf, cbH, c2, pkb);
  vq_out_kernel<<<8192, 256, 0, stream>>>(pkb, Abuf, cb, outq, outidx);
}

// Round 14
// 2067.944 us; speedup vs baseline: 1.3171x; 1.0817x over previous
//
#include <hip/hip_runtime.h>
#include <math.h>

#define DEV __device__ __forceinline__

typedef __attribute__((ext_vector_type(8))) _Float16 f16x8;
typedef __attribute__((ext_vector_type(8))) short short8;
typedef __attribute__((ext_vector_type(4))) float f32x4;

namespace {

constexpr int C = 512;
constexpr int ROWS = 32768;   // B * L
constexpr float LSCALE = 2048.0f;        // lo-plane pre-scale (2^11)
constexpr float LINV   = 1.0f / 2048.0f;
constexpr float F16MIN = 6.1035156e-5f;  // fp16 min normal

// fp32 -> fp16 hi/lo split. h = RTN(x) (flushed to 0 below normal range),
// l = RTN((x - h) * 2^11). Ensures all MFMA inputs are 0 or normal fp16.
DEV void f2hsplit(float x, short& hs, short& ls) {
  _Float16 h = (_Float16)x;
  float hf = (float)h;
  if (fabsf(hf) < F16MIN) { h = (_Float16)0.0f; hf = 0.f; }
  _Float16 l = (_Float16)((x - hf) * LSCALE);
  if (fabsf((float)l) < F16MIN) l = (_Float16)0.0f;
  hs = __builtin_bit_cast(short, h);
  ls = __builtin_bit_cast(short, l);
}

DEV unsigned umn(unsigned a, unsigned b) { return a < b ? a : b; }
DEV unsigned umx(unsigned a, unsigned b) { return a > b ? a : b; }

// monotone key: high 20 bits = sign-flipped fp32 distance, low 12 = col idx.
DEV unsigned packkey(float d, int col) {
  unsigned u = __builtin_bit_cast(unsigned, d);
  u = (u & 0x80000000u) ? ~u : (u | 0x80000000u);
  return (u & 0xFFFFF000u) | (unsigned)col;
}
DEV float unpackd(unsigned k) {
  unsigned u = (k & 0x80000000u) ? (k ^ 0x80000000u) : ~k;
  return __builtin_bit_cast(float, u);
}

// windowed row r -> flat row in (b, y, x) order, for roll by `shift`.
DEV int rowmap(int r, int shift) {
  int b  = r >> 10;
  int w  = (r >> 6) & 15;
  int wy = w >> 2, wx = w & 3;
  int ii = r & 63;
  int iy = ii >> 3, ix = ii & 7;
  int y = (wy * 8 + iy + shift) & 31;
  int x = (wx * 8 + ix + shift) & 31;
  return (b << 10) + (y << 5) + x;
}

DEV int region(int y) { return (y < 24) ? 0 : ((y < 28) ? 1 : 2); }

typedef __attribute__((address_space(1))) const unsigned int gu32;
typedef __attribute__((address_space(3))) unsigned int lu32;
DEV void gload16(const void* g, void* l) {
  __builtin_amdgcn_global_load_lds((gu32*)g, (lu32*)l, 16, 0, 0);
}

// XCD-local hierarchical tile map: each XCD owns a contiguous m-slab;
// within it, groups of GM m-tiles sweep all n-tiles (A-group stays L2-hot).
DEV void tilemap(int Mt, int Nt, int GM, int& mt, int& nt) {
  int bid = blockIdx.y * Mt + blockIdx.x;
  if ((Mt & 7) == 0) {
    int xcd = bid & 7, idx = bid >> 3;
    int Mt8 = Mt >> 3;
    if (GM > Mt8) GM = Mt8;
    int span = GM * Nt;
    int g = idx / span, rem = idx % span;
    nt = rem / GM;
    mt = xcd * Mt8 + g * GM + rem % GM;
  } else {
    mt = blockIdx.x; nt = blockIdx.y;
  }
}

// ---------------- LayerNorm -> fp16 hi/lo planes ---------------------------
__global__ __launch_bounds__(256) void ln_split_kernel(
    const float* __restrict__ src, short* __restrict__ Hp, short* __restrict__ Lp,
    const float* __restrict__ g, const float* __restrict__ b,
    int shift, int windowed) {
  int wid  = (blockIdx.x * 256 + threadIdx.x) >> 6;
  int lane = threadIdx.x & 63;
  if (wid >= ROWS) return;
  int srcRow = windowed ? rowmap(wid, shift) : wid;
  const float* s = src + (size_t)srcRow * C + lane * 8;
  float v[8];
  *(float4*)(v)     = *(const float4*)(s);
  *(float4*)(v + 4) = *(const float4*)(s + 4);
  float sum = 0.f;
#pragma unroll
  for (int j = 0; j < 8; j++) sum += v[j];
#pragma unroll
  for (int o = 32; o >= 1; o >>= 1) sum += __shfl_xor(sum, o);
  float mu = sum * (1.0f / 512.0f);
  float vs = 0.f;
#pragma unroll
  for (int j = 0; j < 8; j++) { float d = v[j] - mu; vs += d * d; }
#pragma unroll
  for (int o = 32; o >= 1; o >>= 1) vs += __shfl_xor(vs, o);
  float rs = rsqrtf(vs * (1.0f / 512.0f) + 1e-5f);
  float gg[8], bb[8];
  *(float4*)gg       = *(const float4*)&g[lane * 8];
  *(float4*)(gg + 4) = *(const float4*)&g[lane * 8 + 4];
  *(float4*)bb       = *(const float4*)&b[lane * 8];
  *(float4*)(bb + 4) = *(const float4*)&b[lane * 8 + 4];
  short8 hv, lv;
#pragma unroll
  for (int j = 0; j < 8; j++) {
    float o8 = (v[j] - mu) * rs * gg[j] + bb[j];
    short hh, ll;
    f2hsplit(o8, hh, ll);
    hv[j] = hh; lv[j] = ll;
  }
  *(short8*)&Hp[(size_t)wid * C + lane * 8] = hv;
  *(short8*)&Lp[(size_t)wid * C + lane * 8] = lv;
}

// ---------------- row sum of squares (codebook) ----------------------------
__global__ __launch_bounds__(256) void rowss_kernel(
    const float* __restrict__ src, float* __restrict__ dst, int nrows) {
  int wid  = (blockIdx.x * 256 + threadIdx.x) >> 6;
  int lane = threadIdx.x & 63;
  if (wid >= nrows) return;
  const float* s = src + (size_t)wid * C + lane * 8;
  float4 a  = *(const float4*)s;
  float4 b4 = *(const float4*)(s + 4);
  float sum = a.x*a.x + a.y*a.y + a.z*a.z + a.w*a.w
            + b4.x*b4.x + b4.y*b4.y + b4.z*b4.z + b4.w*b4.w;
#pragma unroll
  for (int o = 32; o >= 1; o >>= 1) sum += __shfl_xor(sum, o);
  if (lane == 0) dst[wid] = sum;
}

// ---------------- weight transpose + split: W(K,N) -> H/L (N,K) ------------
__global__ __launch_bounds__(256) void wconvT_kernel(
    const float* __restrict__ W, short* __restrict__ Hp, short* __restrict__ Lp,
    int K, int N) {
  __shared__ float t[32][33];
  int tx = threadIdx.x, ty = threadIdx.y;
  int n0 = blockIdx.x * 32, k0 = blockIdx.y * 32;
#pragma unroll
  for (int r = 0; r < 4; r++) {
    int k = ty + r * 8;
    t[k][tx] = W[(size_t)(k0 + k) * N + n0 + tx];
  }
  __syncthreads();
#pragma unroll
  for (int r = 0; r < 4; r++) {
    int n = ty + r * 8;
    short h, l;
    f2hsplit(t[tx][n], h, l);
    Hp[(size_t)(n0 + n) * K + k0 + tx] = h;
    Lp[(size_t)(n0 + n) * K + k0 + tx] = l;
  }
}

// ---------------- codebook split (already N-major) -------------------------
__global__ __launch_bounds__(256) void wconv_kernel(
    const float* __restrict__ W, short* __restrict__ Hp, short* __restrict__ Lp) {
  size_t i = ((size_t)blockIdx.x * 256 + threadIdx.x) * 4;
  float4 a = *(const float4*)&W[i];
  float v[4] = {a.x, a.y, a.z, a.w};
  short hv[4], lv[4];
#pragma unroll
  for (int j = 0; j < 4; j++) f2hsplit(v[j], hv[j], lv[j]);
  *(short4*)&Hp[i] = *(short4*)hv;
  *(short4*)&Lp[i] = *(short4*)lv;
}

// -- fp16-pair MFMA GEMM, 128x128 tile, BK=32, 8 waves, LDS double-buffer ---
// A planes [M][K], B planes [N][K]; C = A * B^T (+ epilogue).
// acc = accH(h*h) + 2^-11 * accL(h*lw + la*h); la/lw are pre-scaled by 2^11.
// EPI: 0 = fp32 out+bias (qkv); 1 = gelu -> hi/lo planes (fc1);
//      2 = +bias+resid fp32 (proj/fc2); 4 = EPI2 + h/l plane store
template <int EPI>
__global__ __launch_bounds__(512) void mgemm(
    const short* __restrict__ Ah, const short* __restrict__ Al,
    const short* __restrict__ Bh, const short* __restrict__ Bl,
    const int K, const float* __restrict__ bias,
    float* __restrict__ outF, short* __restrict__ outH, short* __restrict__ outL,
    const int ldo,
    const float* __restrict__ resid, const int rowOff, const int perm, const int shift) {
  __shared__ short lds[32768];   // 2 buffers x (Ah|Bh|Al|Bl) 128x32 fp16 tiles
  int mt, nt;
  tilemap(gridDim.x, gridDim.y, 4, mt, nt);   // GM=4: 1MB A-group (H+L)
  const int m0 = mt * 128, n0 = nt * 128;
  const int t  = threadIdx.x;
  const int wv = t >> 6, ln = t & 63;
  const int wr = (wv >> 2) * 64, wc = (wv & 3) * 32;   // wave tile 64x32
  const int l15 = ln & 15, l4 = ln >> 4;

  f32x4 accH[4][2], accL[4][2];
#pragma unroll
  for (int mf = 0; mf < 4; mf++)
#pragma unroll
    for (int nf = 0; nf < 2; nf++) {
      accH[mf][nf] = (f32x4){0.f, 0.f, 0.f, 0.f};
      accL[mf][nf] = (f32x4){0.f, 0.f, 0.f, 0.f};
    }

  const int srow = ln >> 2;
  const int scol = ((ln & 3) ^ ((ln >> 3) & 3)) * 8;

  auto stage = [&](int buf, int k0) {
    short* b = lds + buf * 16384;
    size_t ra = (size_t)(m0 + wv * 16 + srow) * K + k0 + scol;
    size_t rb = (size_t)(n0 + wv * 16 + srow) * K + k0 + scol;
    gload16(Ah + ra, b + wv * 512);
    gload16(Bh + rb, b + 4096 + wv * 512);
    gload16(Al + ra, b + 8192 + wv * 512);
    gload16(Bl + rb, b + 12288 + wv * 512);
  };
  auto frag = [&](const short* lt, int rbase) -> f16x8 {
    int r = rbase + l15;
    int kc = l4 ^ ((r >> 1) & 3);
    return *(const f16x8*)(lt + (r >> 4) * 512 + (r & 15) * 32 + kc * 8);
  };

  stage(0, 0);
  __syncthreads();
  int cur = 0;
  for (int k0 = 0; k0 < K; k0 += 32) {
    if (k0 + 32 < K) stage(cur ^ 1, k0 + 32);
    const short* base = lds + cur * 16384;
    f16x8 ah[4], bh[2], bl[2];
#pragma unroll
    for (int mf = 0; mf < 4; mf++) ah[mf] = frag(base, wr + mf * 16);
#pragma unroll
    for (int nf = 0; nf < 2; nf++) bh[nf] = frag(base + 4096, wc + nf * 16);
    __builtin_amdgcn_s_setprio(1);
#pragma unroll
    for (int mf = 0; mf < 4; mf++)
#pragma unroll
      for (int nf = 0; nf < 2; nf++)
        accH[mf][nf] = __builtin_amdgcn_mfma_f32_16x16x32_f16(ah[mf], bh[nf], accH[mf][nf], 0, 0, 0);
    __builtin_amdgcn_s_setprio(0);
#pragma unroll
    for (int nf = 0; nf < 2; nf++) bl[nf] = frag(base + 12288, wc + nf * 16);
    __builtin_amdgcn_s_setprio(1);
#pragma unroll
    for (int mf = 0; mf < 4; mf++)
#pragma unroll
      for (int nf = 0; nf < 2; nf++)
        accL[mf][nf] = __builtin_amdgcn_mfma_f32_16x16x32_f16(ah[mf], bl[nf], accL[mf][nf], 0, 0, 0);
#pragma unroll
    for (int mf = 0; mf < 4; mf++) {
      f16x8 al = frag(base + 8192, wr + mf * 16);
#pragma unroll
      for (int nf = 0; nf < 2; nf++)
        accL[mf][nf] = __builtin_amdgcn_mfma_f32_16x16x32_f16(al, bh[nf], accL[mf][nf], 0, 0, 0);
    }
    __builtin_amdgcn_s_setprio(0);
    __syncthreads();
    cur ^= 1;
  }

  f32x4 acc[4][2];
#pragma unroll
  for (int mf = 0; mf < 4; mf++)
#pragma unroll
    for (int nf = 0; nf < 2; nf++)
#pragma unroll
      for (int r = 0; r < 4; r++)
        acc[mf][nf][r] = fmaf(accL[mf][nf][r], LINV, accH[mf][nf][r]);

  if (EPI == 0) {
#pragma unroll
    for (int mf = 0; mf < 4; mf++)
#pragma unroll
      for (int r = 0; r < 4; r++) {
        int row = m0 + wr + mf * 16 + l4 * 4 + r;
        float* op = outF + (size_t)row * ldo;
#pragma unroll
        for (int nf = 0; nf < 2; nf++) {
          int col = n0 + wc + nf * 16 + l15;
          op[col] = acc[mf][nf][r] + bias[col];
        }
      }
  } else if (EPI == 1) {
#pragma unroll
    for (int mf = 0; mf < 4; mf++)
#pragma unroll
      for (int r = 0; r < 4; r++) {
        int row = m0 + wr + mf * 16 + l4 * 4 + r;
#pragma unroll
        for (int nf = 0; nf < 2; nf++) {
          int col = n0 + wc + nf * 16 + l15;
          float v = acc[mf][nf][r] + bias[col];
          v = 0.5f * v * (1.0f + erff(v * 0.70710678118654752f));
          short h, l;
          f2hsplit(v, h, l);
          outH[(size_t)row * ldo + col] = h;
          outL[(size_t)row * ldo + col] = l;
        }
      }
  } else {  // EPI == 2 or 4
#pragma unroll
    for (int mf = 0; mf < 4; mf++)
#pragma unroll
      for (int r = 0; r < 4; r++) {
        int row = m0 + wr + mf * 16 + l4 * 4 + r;
        int orow = perm ? rowmap(row, shift) : (row + rowOff);
        const float* rp = resid + (size_t)orow * ldo;
        float* op = outF + (size_t)orow * ldo;
#pragma unroll
        for (int nf = 0; nf < 2; nf++) {
          int col = n0 + wc + nf * 16 + l15;
          float v = rp[col] + acc[mf][nf][r] + bias[col];
          op[col] = v;
          if (EPI == 4) {
            short h, l;
            f2hsplit(v, h, l);
            outH[(size_t)orow * ldo + col] = h;
            outL[(size_t)orow * ldo + col] = l;
          }
        }
      }
  }
}

// -- VQ distance GEMM: h*h only, block 128x256, 8 waves of 64x64, BK=32 -----
// 4x4 fragment reuse. Single-buffer, 2 barriers. XCD-grouped tile order
// (GM=8 -> 1MB A-group L2-resident across the 16-n sweep).
// top-2 per 256-col tile emitted as packed keys; exact rescore downstream.
__global__ __launch_bounds__(512) void vqgemm(
    const short* __restrict__ Ah, const short* __restrict__ Bh,
    const float* __restrict__ c2, unsigned* __restrict__ pk) {
  __shared__ short lds[12288];   // A 128x32 (8 chunks) | B 256x32 (16 chunks)
  const int bid = blockIdx.x;
  const int xcd = bid & 7, idx = bid >> 3;
  const int g  = idx >> 7;             // 0..3 (group of 8 m-tiles)
  const int ny = (idx >> 3) & 15;      // 0..15
  const int mi = idx & 7;              // 0..7
  const int m0 = (xcd * 32 + g * 8 + mi) * 128;
  const int n0 = ny * 256;
  const int K = 512;
  const int t  = threadIdx.x;
  const int wv = t >> 6, ln = t & 63;
  const int wr = (wv >> 2) * 64, wc = (wv & 3) * 64;  // wave tile 64x64
  const int l15 = ln & 15, l4 = ln >> 4;

  f32x4 acc[4][4];
#pragma unroll
  for (int mf = 0; mf < 4; mf++)
#pragma unroll
    for (int nf = 0; nf < 4; nf++) acc[mf][nf] = (f32x4){0.f, 0.f, 0.f, 0.f};

  const int srow = ln >> 2;
  const int scol = ((ln & 3) ^ ((ln >> 3) & 3)) * 8;

  short* As = lds;            // 8 chunks
  short* Bs = lds + 4096;     // 16 chunks

  auto frag = [&](const short* lt, int rbase) -> f16x8 {
    int r = rbase + l15;
    int kc = l4 ^ ((r >> 1) & 3);
    return *(const f16x8*)(lt + (r >> 4) * 512 + (r & 15) * 32 + kc * 8);
  };

  for (int k0 = 0; k0 < K; k0 += 32) {
#pragma unroll
    for (int q = 0; q < 3; q++) {
      int s = wv * 3 + q;                 // 0..23: 8 A chunks then 16 B chunks
      int isA = (s < 8);
      int c = isA ? s : (s - 8);
      const short* src = isA ? Ah : Bh;
      short* dst = (isA ? As : Bs) + c * 512;
      int rowbase = (isA ? m0 : n0) + c * 16;
      size_t ga = (size_t)(rowbase + srow) * K + k0 + scol;
      gload16(src + ga, dst);
    }
    __syncthreads();
    f16x8 ah[4], bh[4];
#pragma unroll
    for (int mf = 0; mf < 4; mf++) ah[mf] = frag(As, wr + mf * 16);
#pragma unroll
    for (int nf = 0; nf < 4; nf++) bh[nf] = frag(Bs, wc + nf * 16);
    __builtin_amdgcn_s_setprio(1);
#pragma unroll
    for (int mf = 0; mf < 4; mf++)
#pragma unroll
      for (int nf = 0; nf < 4; nf++)
        acc[mf][nf] = __builtin_amdgcn_mfma_f32_16x16x32_f16(ah[mf], bh[nf], acc[mf][nf], 0, 0, 0);
    __builtin_amdgcn_s_setprio(0);
    __syncthreads();
  }

  // top-2 per row over this 256-col tile
  unsigned* hk = (unsigned*)(void*)lds;   // [128 rows][4 nwaves][2] = 4 KB
#pragma unroll
  for (int mf = 0; mf < 4; mf++)
#pragma unroll
    for (int r = 0; r < 4; r++) {
      int wrow = wr + mf * 16 + l4 * 4 + r;
      unsigned k1 = 0xFFFFFFFFu, k2 = 0xFFFFFFFFu;
#pragma unroll
      for (int nf = 0; nf < 4; nf++) {
        int col = n0 + wc + nf * 16 + l15;
        float d = c2[col] - 2.0f * acc[mf][nf][r];
        unsigned kk = packkey(d, col);
        if (kk < k1) { k2 = k1; k1 = kk; }
        else if (kk < k2) { k2 = kk; }
      }
      // 16-lane (same l4 = same row) top-2 butterfly over the wave's 64 cols
#pragma unroll
      for (int o = 1; o <= 8; o <<= 1) {
        unsigned b1 = (unsigned)__shfl_xor((int)k1, o);
        unsigned b2 = (unsigned)__shfl_xor((int)k2, o);
        unsigned m1 = umn(k1, b1);
        unsigned m2 = umn(umx(k1, b1), umn(k2, b2));
        k1 = m1; k2 = m2;
      }
      if (l15 == 0) {
        hk[wrow * 8 + (wv & 3) * 2 + 0] = k1;
        hk[wrow * 8 + (wv & 3) * 2 + 1] = k2;
      }
    }
  __syncthreads();
  if (t < 128) {
    unsigned q1[4], q2[4];
#pragma unroll
    for (int i = 0; i < 4; i++) {
      q1[i] = hk[t * 8 + i * 2];
      q2[i] = hk[t * 8 + i * 2 + 1];
    }
    unsigned a1 = umn(q1[0], q1[1]);
    unsigned a2 = umn(umx(q1[0], q1[1]), umn(q2[0], q2[1]));
    unsigned b1 = umn(q1[2], q1[3]);
    unsigned b2 = umn(umx(q1[2], q1[3]), umn(q2[2], q2[3]));
    unsigned m1 = umn(a1, b1);
    unsigned m2 = umn(umx(a1, b1), umn(a2, b2));
    size_t base = (size_t)(m0 + t) * 32 + ny * 2;
    pk[base + 0] = m1;
    pk[base + 1] = m2;
  }
}

// ---------------- candidate select + exact fp32 rescore + gather -----------
__global__ __launch_bounds__(256) void vq_out_kernel(
    const unsigned* __restrict__ pk, const float* __restrict__ x,
    const float* __restrict__ cb,
    float* __restrict__ outq, float* __restrict__ outidx) {
  int r = blockIdx.x * 4 + (threadIdx.x >> 6);
  int lane = threadIdx.x & 63;
  unsigned key = (lane < 32) ? pk[(size_t)r * 32 + lane] : 0xFFFFFFFFu;
  unsigned kmin = key;
#pragma unroll
  for (int o = 32; o >= 1; o >>= 1) kmin = umn(kmin, (unsigned)__shfl_xor((int)kmin, o));
  float dmin = unpackd(kmin);
  unsigned long long mask = __ballot(lane < 32 && unpackd(key) <= dmin + 2.0f);

  const float* xr = x + (size_t)r * C + lane * 8;
  float4 xa = *(const float4*)xr;
  float4 xb = *(const float4*)(xr + 4);

  float bestd = 3.4e38f;
  int   besti = 0x7fffffff;
  while (mask) {
    int l = __ffsll(mask) - 1;
    mask &= mask - 1;
    int col = ((unsigned)__shfl((int)key, l)) & 0xFFFu;
    const float* cr = cb + (size_t)col * C + lane * 8;
    float4 ca = *(const float4*)cr;
    float4 cb4 = *(const float4*)(cr + 4);
    float s = 0.f;
    s = fmaf(ca.x, ca.x - 2.f * xa.x, s);
    s = fmaf(ca.y, ca.y - 2.f * xa.y, s);
    s = fmaf(ca.z, ca.z - 2.f * xa.z, s);
    s = fmaf(ca.w, ca.w - 2.f * xa.w, s);
    s = fmaf(cb4.x, cb4.x - 2.f * xb.x, s);
    s = fmaf(cb4.y, cb4.y - 2.f * xb.y, s);
    s = fmaf(cb4.z, cb4.z - 2.f * xb.z, s);
    s = fmaf(cb4.w, cb4.w - 2.f * xb.w, s);
#pragma unroll
    for (int o = 32; o >= 1; o >>= 1) s += __shfl_xor(s, o);
    if (s < bestd || (s == bestd && col < besti)) { bestd = s; besti = col; }
  }
  const float4* src = (const float4*)(cb + (size_t)besti * C + lane * 8);
  float4*       dst = (float4*)(outq + (size_t)r * C + lane * 8);
  dst[0] = src[0];
  dst[1] = src[1];
  if (lane == 0) outidx[r] = (float)besti;
}

// ---------------- fused per-(window, head) attention (fp32) ----------------
// 4x4 per-thread blocking, LDS row stride 68 (2-way banks), pT aliases q.
// Per wave ~272 LDS instrs (vs 630 in the 1x16 mapping) -> VALU-bound.
__global__ __launch_bounds__(256) void attn_kernel(
    const float* __restrict__ qkv,   // chunk-local windowed rows x 1536
    const float* __restrict__ rpb,   // (225, 8)
    short* __restrict__ Hout, short* __restrict__ Lout,  // global windowed rows x 512
    int winOff, int shift) {
  constexpr int LDW = 68;
  __shared__ float q[64 * LDW], k[64 * LDW], v[64 * LDW];   // 52.2 KiB
  float* pT = q;   // pT[j*LDW + i], aliases q after barrier

  int wl = blockIdx.x;
  int h  = blockIdx.y;
  int t  = threadIdx.x;

  const float* base = qkv + (size_t)wl * 64 * 1536 + h * 64;
#pragma unroll
  for (int rep = 0; rep < 4; rep++) {
    int f = t + rep * 256;
    int i = f >> 4, dq = (f & 15) * 4;
    const float* rowp = base + (size_t)i * 1536 + dq;
    float4 qv = *(const float4*)(rowp);
    float4 kv = *(const float4*)(rowp + 512);
    float4 vv = *(const float4*)(rowp + 1024);
    qv.x *= 0.125f; qv.y *= 0.125f; qv.z *= 0.125f; qv.w *= 0.125f;
    *(float4*)&q[i * LDW + dq] = qv;
    *(float4*)&k[i * LDW + dq] = kv;
    *(float4*)&v[i * LDW + dq] = vv;
  }
  __syncthreads();

  const int rgrp = t >> 4, cgrp = t & 15;
  const int wim = (winOff + wl) & 15;
  const int wy = wim >> 2, wx = wim & 3;

  // QK^T: rows i = rgrp*4+r, cols j = cgrp + 16*c
  float s[4][4];
#pragma unroll
  for (int r = 0; r < 4; r++)
#pragma unroll
    for (int c = 0; c < 4; c++) s[r][c] = 0.f;
#pragma unroll
  for (int dch = 0; dch < 16; dch++) {
    float4 q4[4], k4[4];
#pragma unroll
    for (int r = 0; r < 4; r++) q4[r] = *(float4*)&q[(rgrp * 4 + r) * LDW + dch * 4];
#pragma unroll
    for (int c = 0; c < 4; c++) k4[c] = *(float4*)&k[(cgrp + 16 * c) * LDW + dch * 4];
#pragma unroll
    for (int r = 0; r < 4; r++)
#pragma unroll
      for (int c = 0; c < 4; c++) {
        s[r][c] = fmaf(q4[r].x, k4[c].x, s[r][c]);
        s[r][c] = fmaf(q4[r].y, k4[c].y, s[r][c]);
        s[r][c] = fmaf(q4[r].z, k4[c].z, s[r][c]);
        s[r][c] = fmaf(q4[r].w, k4[c].w, s[r][c]);
      }
  }
  // bias + mask
#pragma unroll
  for (int r = 0; r < 4; r++) {
    int i = rgrp * 4 + r;
    int iy = i >> 3, ix = i & 7;
    int ci = shift ? (region(wy * 8 + iy) * 3 + region(wx * 8 + ix)) : 0;
#pragma unroll
    for (int c = 0; c < 4; c++) {
      int j = cgrp + 16 * c;
      int jy = j >> 3, jx = j & 7;
      s[r][c] += rpb[((iy - jy + 7) * 15 + (ix - jx + 7)) * 8 + h];
      if (shift) {
        int cj = region(wy * 8 + jy) * 3 + region(wx * 8 + jx);
        if (ci != cj) s[r][c] -= 100.0f;
      }
    }
  }
  // softmax per row (16-lane group = one row set)
  float p[4][4];
#pragma unroll
  for (int r = 0; r < 4; r++) {
    float mx = fmaxf(fmaxf(s[r][0], s[r][1]), fmaxf(s[r][2], s[r][3]));
#pragma unroll
    for (int o = 1; o <= 8; o <<= 1) mx = fmaxf(mx, __shfl_xor(mx, o));
    float sum = 0.f;
#pragma unroll
    for (int c = 0; c < 4; c++) { p[r][c] = expf(s[r][c] - mx); sum += p[r][c]; }
#pragma unroll
    for (int o = 1; o <= 8; o <<= 1) sum += __shfl_xor(sum, o);
    float inv = 1.0f / sum;
#pragma unroll
    for (int c = 0; c < 4; c++) p[r][c] *= inv;
  }
  __syncthreads();   // all q reads done before pT (aliasing q) is written
  // write pT[j][i-block]: 4 consecutive rows -> one float4 per col
#pragma unroll
  for (int c = 0; c < 4; c++) {
    int j = cgrp + 16 * c;
    float4 pw;
    pw.x = p[0][c]; pw.y = p[1][c]; pw.z = p[2][c]; pw.w = p[3][c];
    *(float4*)&pT[j * LDW + rgrp * 4] = pw;
  }
  __syncthreads();

  // PV: rows i = rgrp*4+r, d-block = cgrp*4..+4
  float o4[4][4];
#pragma unroll
  for (int r = 0; r < 4; r++)
#pragma unroll
    for (int e = 0; e < 4; e++) o4[r][e] = 0.f;
#pragma unroll 8
  for (int j = 0; j < 64; j++) {
    float4 pv4 = *(float4*)&pT[j * LDW + rgrp * 4];
    float4 vv4 = *(float4*)&v[j * LDW + cgrp * 4];
    o4[0][0] = fmaf(pv4.x, vv4.x, o4[0][0]);
    o4[0][1] = fmaf(pv4.x, vv4.y, o4[0][1]);
    o4[0][2] = fmaf(pv4.x, vv4.z, o4[0][2]);
    o4[0][3] = fmaf(pv4.x, vv4.w, o4[0][3]);
    o4[1][0] = fmaf(pv4.y, vv4.x, o4[1][0]);
    o4[1][1] = fmaf(pv4.y, vv4.y, o4[1][1]);
    o4[1][2] = fmaf(pv4.y, vv4.z, o4[1][2]);
    o4[1][3] = fmaf(pv4.y, vv4.w, o4[1][3]);
    o4[2][0] = fmaf(pv4.z, vv4.x, o4[2][0]);
    o4[2][1] = fmaf(pv4.z, vv4.y, o4[2][1]);
    o4[2][2] = fmaf(pv4.z, vv4.z, o4[2][2]);
    o4[2][3] = fmaf(pv4.z, vv4.w, o4[2][3]);
    o4[3][0] = fmaf(pv4.w, vv4.x, o4[3][0]);
    o4[3][1] = fmaf(pv4.w, vv4.y, o4[3][1]);
    o4[3][2] = fmaf(pv4.w, vv4.z, o4[3][2]);
    o4[3][3] = fmaf(pv4.w, vv4.w, o4[3][3]);
  }
  size_t rowbase = (size_t)(winOff + wl) * 64;
#pragma unroll
  for (int r = 0; r < 4; r++) {
    int i = rgrp * 4 + r;
    size_t ob = (rowbase + i) * 512 + h * 64 + cgrp * 4;
    short hv4[4], lv4[4];
#pragma unroll
    for (int e = 0; e < 4; e++) f2hsplit(o4[r][e], hv4[e], lv4[e]);
    *(short4*)&Hout[ob] = *(short4*)hv4;
    *(short4*)&Lout[ob] = *(short4*)lv4;
  }
}

}  // namespace

extern "C" void kernel_launch(void* const* d_in, const int* in_sizes, int n_in,
                              void* d_out, int out_size, void* d_ws, size_t ws_size,
                              hipStream_t stream) {
  const float* x_in = (const float*)d_in[0];
  const float* n1g  = (const float*)d_in[1];
  const float* n1b  = (const float*)d_in[2];
  const float* qkvw = (const float*)d_in[3];
  const float* qkvb = (const float*)d_in[4];
  const float* rpb  = (const float*)d_in[5];
  const float* pw   = (const float*)d_in[6];
  const float* pb   = (const float*)d_in[7];
  const float* n2g  = (const float*)d_in[8];
  const float* n2b  = (const float*)d_in[9];
  const float* f1w  = (const float*)d_in[10];
  const float* f1b  = (const float*)d_in[11];
  const float* f2w  = (const float*)d_in[12];
  const float* f2b_ = (const float*)d_in[13];
  const float* cb   = (const float*)d_in[14];

  float* outq   = (float*)d_out;
  float* outidx = outq + 16777216;
  short* Hbuf = (short*)d_out;                 // hi plane: first 32MB of outq
  short* Lbuf = Hbuf + (size_t)ROWS * 512;     // lo plane: second 32MB

  char* ws = (char*)d_ws;
  float* Abuf = (float*)ws;                               // 64MiB residual stream
  short* Wb   = (short*)(ws + ((size_t)64 << 20));        // 32MiB weight planes
  char*  Cbuf = ws + ((size_t)96 << 20);                  // chunk scratch
  const int Rrows = (ws_size >= ((size_t)232 << 20)) ? 16384
                  : (ws_size >= ((size_t)160 << 20)) ? 8192
                  : (ws_size >= ((size_t)128 << 20)) ? 4096 : 2048;

  const int SZ_QKV = 512 * 1536, SZ_P = 512 * 512, SZ_F1 = 512 * 2048, SZ_F2 = 2048 * 512;
  const int PB = (SZ_QKV + SZ_P + SZ_F1 + SZ_F2) * 2;
  short* cbH = Wb + (size_t)2 * PB;
  short* cbL = cbH + 4096 * 512;

  // ---- one-time (per launch) weight transpose + split ----
  for (int blk = 0; blk < 2; blk++) {
    short* base = Wb + (size_t)blk * PB;
    short* qH = base;          short* qL = qH + SZ_QKV;
    short* pH = qL + SZ_QKV;   short* pL = pH + SZ_P;
    short* f1H = pL + SZ_P;    short* f1L = f1H + SZ_F1;
    short* f2H = f1L + SZ_F1;  short* f2L = f2H + SZ_F2;
    wconvT_kernel<<<dim3(48, 16), dim3(32, 8), 0, stream>>>(qkvw + (size_t)blk * SZ_QKV, qH, qL, 512, 1536);
    wconvT_kernel<<<dim3(16, 16), dim3(32, 8), 0, stream>>>(pw + (size_t)blk * SZ_P, pH, pL, 512, 512);
    wconvT_kernel<<<dim3(64, 16), dim3(32, 8), 0, stream>>>(f1w + (size_t)blk * SZ_F1, f1H, f1L, 512, 2048);
    wconvT_kernel<<<dim3(16, 64), dim3(32, 8), 0, stream>>>(f2w + (size_t)blk * SZ_F2, f2H, f2L, 2048, 512);
  }
  wconv_kernel<<<2048, 256, 0, stream>>>(cb, cbH, cbL);

  const int nch = ROWS / Rrows;
  for (int blk = 0; blk < 2; blk++) {
    short* base = Wb + (size_t)blk * PB;
    short* qH = base;          short* qL = qH + SZ_QKV;
    short* pH = qL + SZ_QKV;   short* pL = pH + SZ_P;
    short* f1H = pL + SZ_P;    short* f1L = f1H + SZ_F1;
    short* f2H = f1L + SZ_F1;  short* f2L = f2H + SZ_F2;
    const float* xcur = blk ? (const float*)Abuf : x_in;
    int shift = blk ? 4 : 0;

    // LN1 + shift + window partition -> hi/lo planes (windowed order)
    ln_split_kernel<<<8192, 256, 0, stream>>>(xcur, Hbuf, Lbuf, n1g + blk * 512, n1b + blk * 512, shift, 1);

    // qkv GEMM (fp32 out) + attention (writes planes back in place)
    float* Cq = (float*)Cbuf;
    for (int ch = 0; ch < nch; ch++) {
      int r0 = ch * Rrows;
      mgemm<0><<<dim3(Rrows / 128, 12), 512, 0, stream>>>(
          Hbuf + (size_t)r0 * 512, Lbuf + (size_t)r0 * 512, qH, qL, 512,
          qkvb + blk * 1536, Cq, nullptr, nullptr, 1536,
          nullptr, 0, 0, 0);
      attn_kernel<<<dim3(Rrows / 64, 8), 256, 0, stream>>>(
          Cq, rpb + blk * 1800, Hbuf, Lbuf, r0 >> 6, shift);
    }

    // proj + window reverse + unshift + residual -> Abuf (fp32)
    mgemm<2><<<dim3(256, 4), 512, 0, stream>>>(
        Hbuf, Lbuf, pH, pL, 512, pb + blk * 512,
        Abuf, nullptr, nullptr, 512,
        blk ? (const float*)Abuf : x_in, 0, 1, shift);

    // LN2 -> planes (identity order)
    ln_split_kernel<<<8192, 256, 0, stream>>>(Abuf, Hbuf, Lbuf, n2g + blk * 512, n2b + blk * 512, 0, 0);

    // MLP; blk==1 fc2 also emits h/l planes (fused split for VQ)
    short* gh = (short*)Cbuf;
    short* gl = gh + (size_t)Rrows * 2048;
    for (int ch = 0; ch < nch; ch++) {
      int r0 = ch * Rrows;
      mgemm<1><<<dim3(Rrows / 128, 16), 512, 0, stream>>>(
          Hbuf + (size_t)r0 * 512, Lbuf + (size_t)r0 * 512, f1H, f1L, 512,
          f1b + blk * 2048, nullptr, gh, gl, 2048,
          nullptr, 0, 0, 0);
      if (blk == 0) {
        mgemm<2><<<dim3(Rrows / 128, 4), 512, 0, stream>>>(
            gh, gl, f2H, f2L, 2048, f2b_ + blk * 512,
            Abuf, nullptr, nullptr, 512,
            Abuf, r0, 0, 0);
      } else {
        mgemm<4><<<dim3(Rrows / 128, 4), 512, 0, stream>>>(
            gh, gl, f2H, f2L, 2048, f2b_ + blk * 512,
            Abuf, Hbuf, Lbuf, 512,
            Abuf, r0, 0, 0);
      }
    }
  }

  // ---- VQ: approx top-2/tile via single-pass fp16 GEMM, exact rescore ----
  float*    c2  = (float*)Cbuf;                              // 16 KB
  unsigned* pkb = (unsigned*)(Cbuf + ((size_t)64 << 10));    // 4 MiB: 32768 x 32 keys
  rowss_kernel<<<1024, 256, 0, stream>>>(cb, c2, 4096);
  vqgemm<<<4096, 512, 0, stream>>>(Hbuf, cbH, c2, pkb);
  vq_out_kernel<<<8192, 256, 0, stream>>>(pkb, Abuf, cb, outq, outidx);
}